// Round 2
// baseline (3134.990 us; speedup 1.0000x reference)
//
#include <hip/hip_runtime.h>

#define D 256
#define NKEYS 50000
#define BQ 2048
#define NT_SIM 512
#define NCHUNK 98            // ceil(50000/512)
#define NCAND 16             // rescored candidates per query
#define NEG_INF (-3.402823466e38f)
#define DNEG_INF (-1.0e300)

// ---------- Kernel 1: q = query @ W^T + b (fp64 accum), L2-normalize ----------
// Stores fp32 qn (fast path) and fp64 q64n (exact rescore path).
__global__ __launch_bounds__(256) void qnorm_kernel(const float* __restrict__ query,
                                                    const float* __restrict__ W,
                                                    const float* __restrict__ b,
                                                    float* __restrict__ qn,
                                                    double* __restrict__ q64n) {
  __shared__ __align__(16) float As[32][20];
  __shared__ __align__(16) float Bs[256][20];
  const int tid = threadIdx.x;
  const int qt = tid >> 5;   // 0..7 -> rows qt*4+i
  const int nt = tid & 31;   // cols nt + 32*j, j<8
  const int m0 = blockIdx.x * 32;

  double acc[4][8];
#pragma unroll
  for (int i = 0; i < 4; i++)
#pragma unroll
    for (int j = 0; j < 8; j++) acc[i][j] = 0.0;

  for (int k0 = 0; k0 < D; k0 += 16) {
    if (tid < 128) {
      int r = tid >> 2, f = tid & 3;
      *(float4*)(&As[r][f * 4]) = *(const float4*)(&query[(m0 + r) * D + k0 + f * 4]);
    }
#pragma unroll
    for (int i = 0; i < 4; i++) {
      int r = (tid >> 2) + 64 * i, f = tid & 3;
      *(float4*)(&Bs[r][f * 4]) = *(const float4*)(&W[r * D + k0 + f * 4]);
    }
    __syncthreads();
#pragma unroll
    for (int kk = 0; kk < 16; kk += 4) {
      float4 af[4];
#pragma unroll
      for (int i = 0; i < 4; i++) af[i] = *(const float4*)(&As[qt * 4 + i][kk]);
#pragma unroll
      for (int j = 0; j < 8; j++) {
        float4 bf = *(const float4*)(&Bs[nt + 32 * j][kk]);
#pragma unroll
        for (int i = 0; i < 4; i++) {
          acc[i][j] = fma((double)af[i].x, (double)bf.x, acc[i][j]);
          acc[i][j] = fma((double)af[i].y, (double)bf.y, acc[i][j]);
          acc[i][j] = fma((double)af[i].z, (double)bf.z, acc[i][j]);
          acc[i][j] = fma((double)af[i].w, (double)bf.w, acc[i][j]);
        }
      }
    }
    __syncthreads();
  }
  double bias[8];
#pragma unroll
  for (int j = 0; j < 8; j++) bias[j] = (double)b[nt + 32 * j];
#pragma unroll
  for (int i = 0; i < 4; i++)
#pragma unroll
    for (int j = 0; j < 8; j++) acc[i][j] += bias[j];

#pragma unroll
  for (int i = 0; i < 4; i++) {
    double s = 0.0;
#pragma unroll
    for (int j = 0; j < 8; j++) s = fma(acc[i][j], acc[i][j], s);
#pragma unroll
    for (int m = 16; m; m >>= 1) s += __shfl_xor(s, m, 32);
    double den = fmax(sqrt(s), 1e-12);
    int row = m0 + qt * 4 + i;
#pragma unroll
    for (int j = 0; j < 8; j++) {
      double v = acc[i][j] / den;
      qn[row * D + nt + 32 * j] = (float)v;
      q64n[row * D + nt + 32 * j] = v;
    }
  }
}

// ---------- Kernel 2: per-key inverse norm (fp64 accum), fp32+fp64 out ----------
__global__ __launch_bounds__(256) void knorm_kernel(const float* __restrict__ keys,
                                                    float* __restrict__ kinvf,
                                                    double* __restrict__ kinv64) {
  int wave = threadIdx.x >> 6, lane = threadIdx.x & 63;
  int row = blockIdx.x * 4 + wave;
  if (row >= NKEYS) return;
  float4 v = *(const float4*)(&keys[row * D + lane * 4]);
  double s = (double)v.x * v.x + (double)v.y * v.y + (double)v.z * v.z + (double)v.w * v.w;
#pragma unroll
  for (int m = 32; m; m >>= 1) s += __shfl_xor(s, m, 64);
  if (lane == 0) {
    double inv = 1.0 / fmax(sqrt(s), 1e-12);
    kinvf[row] = (float)inv;
    kinv64[row] = inv;
  }
}

// ---------- Kernel 3: usage copy ----------
__global__ void usage_copy_kernel(const float* __restrict__ usage, float* __restrict__ out_u) {
  int i = blockIdx.x * 256 + threadIdx.x;
  if (i < NKEYS) out_u[i] = usage[i];
}

// ---------- Kernel 4: sim GEMM (fp32) + fused per-block top-8 candidates ----------
__global__ __launch_bounds__(256, 2) void sim_topk_kernel(const float* __restrict__ qn,
                                                          const float* __restrict__ keys,
                                                          const float* __restrict__ kinvf,
                                                          float* __restrict__ cand_s,
                                                          int* __restrict__ cand_i) {
  __shared__ __align__(16) float As[64][20];
  __shared__ __align__(16) float Bs[512][20];
  const int tid = threadIdx.x;
  const int qt = tid >> 5;  // 8 groups -> rows qt*8+i
  const int nt = tid & 31;  // cols nt + 32*j, j<16
  const int n0 = blockIdx.x * NT_SIM;
  const int m0 = blockIdx.y * 64;

  float acc[8][16];
#pragma unroll
  for (int i = 0; i < 8; i++)
#pragma unroll
    for (int j = 0; j < 16; j++) acc[i][j] = 0.f;

  for (int k0 = 0; k0 < D; k0 += 16) {
    {
      int r = tid >> 2, f = tid & 3;
      *(float4*)(&As[r][f * 4]) = *(const float4*)(&qn[(m0 + r) * D + k0 + f * 4]);
    }
#pragma unroll
    for (int i = 0; i < 8; i++) {
      int r = (tid >> 2) + 64 * i, f = tid & 3;
      int gr = n0 + r;
      float4 v = make_float4(0.f, 0.f, 0.f, 0.f);
      if (gr < NKEYS) v = *(const float4*)(&keys[(long long)gr * D + k0 + f * 4]);
      *(float4*)(&Bs[r][f * 4]) = v;
    }
    __syncthreads();
#pragma unroll
    for (int kk = 0; kk < 16; kk += 4) {
      float4 af[8];
#pragma unroll
      for (int i = 0; i < 8; i++) af[i] = *(const float4*)(&As[qt * 8 + i][kk]);
#pragma unroll
      for (int j = 0; j < 16; j++) {
        float4 bf = *(const float4*)(&Bs[nt + 32 * j][kk]);
#pragma unroll
        for (int i = 0; i < 8; i++) {
          acc[i][j] = fmaf(af[i].x, bf.x, acc[i][j]);
          acc[i][j] = fmaf(af[i].y, bf.y, acc[i][j]);
          acc[i][j] = fmaf(af[i].z, bf.z, acc[i][j]);
          acc[i][j] = fmaf(af[i].w, bf.w, acc[i][j]);
        }
      }
    }
    __syncthreads();
  }

  int cols[16];
  float inv[16];
#pragma unroll
  for (int j = 0; j < 16; j++) {
    int c = n0 + nt + 32 * j;
    cols[j] = c;
    inv[j] = (c < NKEYS) ? kinvf[c] : 0.f;
  }
#pragma unroll
  for (int i = 0; i < 8; i++)
#pragma unroll
    for (int j = 0; j < 16; j++)
      acc[i][j] = (cols[j] < NKEYS) ? acc[i][j] * inv[j] : NEG_INF;

#pragma unroll
  for (int i = 0; i < 8; i++) {
    int row = m0 + qt * 8 + i;
    int base = row * (NCHUNK * 8) + blockIdx.x * 8;
#pragma unroll 1
    for (int r = 0; r < 8; r++) {
      float bv = NEG_INF;
      int bi = 0x7fffffff;
#pragma unroll
      for (int j = 0; j < 16; j++) {
        if (acc[i][j] > bv || (acc[i][j] == bv && cols[j] < bi)) { bv = acc[i][j]; bi = cols[j]; }
      }
#pragma unroll
      for (int m = 16; m; m >>= 1) {
        float ov = __shfl_xor(bv, m, 32);
        int oi = __shfl_xor(bi, m, 32);
        if (ov > bv || (ov == bv && oi < bi)) { bv = ov; bi = oi; }
      }
      if (nt == r) { cand_s[base + r] = bv; cand_i[base + r] = bi; }
#pragma unroll
      for (int j = 0; j < 16; j++)
        if (cols[j] == bi) acc[i][j] = NEG_INF;
    }
  }
}

// ---------- Kernel 5: merge candidates -> fp32 top-16 indices ----------
__global__ __launch_bounds__(256) void merge_kernel(const float* __restrict__ cand_s,
                                                    const int* __restrict__ cand_i,
                                                    int* __restrict__ fidx16) {
  const int q = blockIdx.x;
  const int tid = threadIdx.x;
  const int NC = NCHUNK * 8;  // 784
  float lv[4];
  int li[4];
#pragma unroll
  for (int s = 0; s < 4; s++) {
    int c = tid + 256 * s;
    if (c < NC) { lv[s] = cand_s[q * NC + c]; li[s] = cand_i[q * NC + c]; }
    else        { lv[s] = NEG_INF; li[s] = 0x7fffffff; }
  }
  __shared__ float swv[4];
  __shared__ int   swi[4];
  __shared__ float wvs;
  __shared__ int   wis;
  int wave = tid >> 6, lane = tid & 63;
#pragma unroll 1
  for (int r = 0; r < NCAND; r++) {
    float bv = NEG_INF;
    int bi = 0x7fffffff;
#pragma unroll
    for (int s = 0; s < 4; s++)
      if (lv[s] > bv || (lv[s] == bv && li[s] < bi)) { bv = lv[s]; bi = li[s]; }
#pragma unroll
    for (int m = 32; m; m >>= 1) {
      float ov = __shfl_xor(bv, m, 64);
      int oi = __shfl_xor(bi, m, 64);
      if (ov > bv || (ov == bv && oi < bi)) { bv = ov; bi = oi; }
    }
    if (lane == 0) { swv[wave] = bv; swi[wave] = bi; }
    __syncthreads();
    if (tid == 0) {
      float fv = swv[0];
      int fi = swi[0];
#pragma unroll
      for (int w = 1; w < 4; w++)
        if (swv[w] > fv || (swv[w] == fv && swi[w] < fi)) { fv = swv[w]; fi = swi[w]; }
      wvs = fv; wis = fi;
    }
    __syncthreads();
    int fi = wis;
    if (tid == r) fidx16[q * NCAND + r] = fi;
#pragma unroll
    for (int s = 0; s < 4; s++)
      if (li[s] == fi) lv[s] = NEG_INF;
  }
}

// ---------- Kernel 6: fp64 exact rescore of 16 candidates -> final top-8 ----------
// 1 block per query, 256 threads: group g=tid>>4 handles candidate g,
// lane-in-group l=tid&15 handles dims l*16..l*16+15.
__global__ __launch_bounds__(256) void rescore_kernel(const double* __restrict__ q64n,
                                                      const float* __restrict__ keys,
                                                      const double* __restrict__ kinv64,
                                                      const int* __restrict__ fidx16,
                                                      float* __restrict__ scores_out,
                                                      int* __restrict__ fidx8,
                                                      float* __restrict__ usage_out) {
  const int q = blockIdx.x;
  const int tid = threadIdx.x;
  const int g = tid >> 4, l = tid & 15;
  const int idx = fidx16[q * NCAND + g];

  double s = 0.0;
  const double* qrow = &q64n[(long long)q * D + l * 16];
  const float* krow = &keys[(long long)idx * D + l * 16];
#pragma unroll
  for (int t = 0; t < 16; t++) s = fma(qrow[t], (double)krow[t], s);
#pragma unroll
  for (int m = 8; m; m >>= 1) s += __shfl_xor(s, m, 16);

  __shared__ double sc[NCAND];
  __shared__ int    si[NCAND];
  __shared__ double s8[8];
  __shared__ int    f8[8];
  if (l == 0) { sc[g] = s * kinv64[idx]; si[g] = idx; }
  __syncthreads();
  if (tid == 0) {
#pragma unroll 1
    for (int r = 0; r < 8; r++) {
      double bv = DNEG_INF;
      int bi = 0x7fffffff, bg = -1;
#pragma unroll
      for (int t = 0; t < NCAND; t++) {
        if (sc[t] > bv || (sc[t] == bv && si[t] < bi)) { bv = sc[t]; bi = si[t]; bg = t; }
      }
      s8[r] = bv; f8[r] = bi;
      sc[bg] = DNEG_INF;
    }
  }
  __syncthreads();
  if (tid < 8) {
    scores_out[q * 8 + tid] = (float)s8[tid];
    fidx8[q * 8 + tid] = f8[tid];
    atomicAdd(&usage_out[f8[tid]], 1.0f);
  }
}

// ---------- Kernel 7: gather retrieved values ----------
__global__ __launch_bounds__(256) void gather_kernel(const float* __restrict__ values,
                                                     const int* __restrict__ fidx8,
                                                     float* __restrict__ out_rv) {
  int wave = threadIdx.x >> 6, lane = threadIdx.x & 63;
  int row = blockIdx.x * 4 + wave;  // q*8+rank
  int idx = fidx8[row];
  float4 v = *(const float4*)(&values[(long long)idx * D + lane * 4]);
  *(float4*)(&out_rv[(long long)row * D + lane * 4]) = v;
}

extern "C" void kernel_launch(void* const* d_in, const int* in_sizes, int n_in,
                              void* d_out, int out_size, void* d_ws, size_t ws_size,
                              hipStream_t stream) {
  (void)in_sizes; (void)n_in; (void)out_size; (void)ws_size;
  const float* query  = (const float*)d_in[0];
  const float* W      = (const float*)d_in[1];
  const float* b      = (const float*)d_in[2];
  const float* keys   = (const float*)d_in[3];
  const float* values = (const float*)d_in[4];
  const float* usage  = (const float*)d_in[5];

  float* out    = (float*)d_out;
  float* out_rv = out;                    // 2048*8*256
  float* out_sc = out + BQ * 8 * D;       // 2048*8
  float* out_us = out_sc + BQ * 8;        // 50000

  // workspace layout (doubles first for 8B alignment)
  double* q64n   = (double*)d_ws;                   // 524288 d
  double* kinv64 = q64n + BQ * D;                   // 50000 d
  float*  qn     = (float*)(kinv64 + NKEYS);        // 524288 f
  float*  kinvf  = qn + BQ * D;                     // 50000 f
  float*  cand_s = kinvf + NKEYS;                   // 2048*784 f
  int*    cand_i = (int*)(cand_s + BQ * NCHUNK * 8);// 2048*784 i
  int*    fidx16 = cand_i + BQ * NCHUNK * 8;        // 2048*16 i
  int*    fidx8  = fidx16 + BQ * NCAND;             // 2048*8 i

  hipLaunchKernelGGL(qnorm_kernel, dim3(BQ / 32), dim3(256), 0, stream, query, W, b, qn, q64n);
  hipLaunchKernelGGL(knorm_kernel, dim3(NKEYS / 4 + 1), dim3(256), 0, stream, keys, kinvf, kinv64);
  hipLaunchKernelGGL(usage_copy_kernel, dim3((NKEYS + 255) / 256), dim3(256), 0, stream, usage, out_us);
  hipLaunchKernelGGL(sim_topk_kernel, dim3(NCHUNK, BQ / 64), dim3(256), 0, stream, qn, keys, kinvf, cand_s, cand_i);
  hipLaunchKernelGGL(merge_kernel, dim3(BQ), dim3(256), 0, stream, cand_s, cand_i, fidx16);
  hipLaunchKernelGGL(rescore_kernel, dim3(BQ), dim3(256), 0, stream, q64n, keys, kinv64, fidx16, out_sc, fidx8, out_us);
  hipLaunchKernelGGL(gather_kernel, dim3(BQ * 8 / 4), dim3(256), 0, stream, values, fidx8, out_rv);
}

// Round 3
// 2474.193 us; speedup vs baseline: 1.2671x; 1.2671x over previous
//
#include <hip/hip_runtime.h>

#define D 256
#define NKEYS 50000
#define BQ 2048
#define NT_SIM 512
#define NCHUNK 98            // ceil(50000/512)
#define NCAND 16             // rescored candidates per query
#define NEG_INF (-3.402823466e38f)
#define DNEG_INF (-1.0e300)

// ---------- Kernel 1: q = query @ W^T + b (fp64 accum), L2-normalize ----------
// Stores fp32 qn (fast path) and fp64 q64n (exact rescore path).
__global__ __launch_bounds__(256) void qnorm_kernel(const float* __restrict__ query,
                                                    const float* __restrict__ W,
                                                    const float* __restrict__ b,
                                                    float* __restrict__ qn,
                                                    double* __restrict__ q64n) {
  __shared__ __align__(16) float As[32][20];
  __shared__ __align__(16) float Bs[256][20];
  const int tid = threadIdx.x;
  const int qt = tid >> 5;   // 0..7 -> rows qt*4+i
  const int nt = tid & 31;   // cols nt + 32*j, j<8
  const int m0 = blockIdx.x * 32;

  double acc[4][8];
#pragma unroll
  for (int i = 0; i < 4; i++)
#pragma unroll
    for (int j = 0; j < 8; j++) acc[i][j] = 0.0;

  for (int k0 = 0; k0 < D; k0 += 16) {
    if (tid < 128) {
      int r = tid >> 2, f = tid & 3;
      *(float4*)(&As[r][f * 4]) = *(const float4*)(&query[(m0 + r) * D + k0 + f * 4]);
    }
#pragma unroll
    for (int i = 0; i < 4; i++) {
      int r = (tid >> 2) + 64 * i, f = tid & 3;
      *(float4*)(&Bs[r][f * 4]) = *(const float4*)(&W[r * D + k0 + f * 4]);
    }
    __syncthreads();
#pragma unroll
    for (int kk = 0; kk < 16; kk += 4) {
      float4 af[4];
#pragma unroll
      for (int i = 0; i < 4; i++) af[i] = *(const float4*)(&As[qt * 4 + i][kk]);
#pragma unroll
      for (int j = 0; j < 8; j++) {
        float4 bf = *(const float4*)(&Bs[nt + 32 * j][kk]);
#pragma unroll
        for (int i = 0; i < 4; i++) {
          acc[i][j] = fma((double)af[i].x, (double)bf.x, acc[i][j]);
          acc[i][j] = fma((double)af[i].y, (double)bf.y, acc[i][j]);
          acc[i][j] = fma((double)af[i].z, (double)bf.z, acc[i][j]);
          acc[i][j] = fma((double)af[i].w, (double)bf.w, acc[i][j]);
        }
      }
    }
    __syncthreads();
  }
  double bias[8];
#pragma unroll
  for (int j = 0; j < 8; j++) bias[j] = (double)b[nt + 32 * j];
#pragma unroll
  for (int i = 0; i < 4; i++)
#pragma unroll
    for (int j = 0; j < 8; j++) acc[i][j] += bias[j];

#pragma unroll
  for (int i = 0; i < 4; i++) {
    double s = 0.0;
#pragma unroll
    for (int j = 0; j < 8; j++) s = fma(acc[i][j], acc[i][j], s);
#pragma unroll
    for (int m = 16; m; m >>= 1) s += __shfl_xor(s, m, 32);
    double den = fmax(sqrt(s), 1e-12);
    int row = m0 + qt * 4 + i;
#pragma unroll
    for (int j = 0; j < 8; j++) {
      double v = acc[i][j] / den;
      qn[row * D + nt + 32 * j] = (float)v;
      q64n[row * D + nt + 32 * j] = v;
    }
  }
}

// ---------- Kernel 2: per-key inverse norm (fp64 accum), fp32+fp64 out ----------
__global__ __launch_bounds__(256) void knorm_kernel(const float* __restrict__ keys,
                                                    float* __restrict__ kinvf,
                                                    double* __restrict__ kinv64) {
  int wave = threadIdx.x >> 6, lane = threadIdx.x & 63;
  int row = blockIdx.x * 4 + wave;
  if (row >= NKEYS) return;
  float4 v = *(const float4*)(&keys[row * D + lane * 4]);
  double s = (double)v.x * v.x + (double)v.y * v.y + (double)v.z * v.z + (double)v.w * v.w;
#pragma unroll
  for (int m = 32; m; m >>= 1) s += __shfl_xor(s, m, 64);
  if (lane == 0) {
    double inv = 1.0 / fmax(sqrt(s), 1e-12);
    kinvf[row] = (float)inv;
    kinv64[row] = inv;
  }
}

// ---------- Kernel 3: usage copy ----------
__global__ void usage_copy_kernel(const float* __restrict__ usage, float* __restrict__ out_u) {
  int i = blockIdx.x * 256 + threadIdx.x;
  if (i < NKEYS) out_u[i] = usage[i];
}

// ---------- Kernel 4: sim GEMM (fp32) + fused per-block top-8 candidates ----------
// launch_bounds(256,1): allow full VGPR budget so acc[8][16] stays in registers.
__global__ __launch_bounds__(256, 1) void sim_topk_kernel(const float* __restrict__ qn,
                                                          const float* __restrict__ keys,
                                                          const float* __restrict__ kinvf,
                                                          float* __restrict__ cand_s,
                                                          int* __restrict__ cand_i) {
  __shared__ __align__(16) float As[64][20];
  __shared__ __align__(16) float Bs[512][20];
  const int tid = threadIdx.x;
  const int qt = tid >> 5;  // 8 groups -> rows qt*8+i
  const int nt = tid & 31;  // cols nt + 32*j, j<16
  const int n0 = blockIdx.x * NT_SIM;
  const int m0 = blockIdx.y * 64;

  float acc[8][16];
#pragma unroll
  for (int i = 0; i < 8; i++)
#pragma unroll
    for (int j = 0; j < 16; j++) acc[i][j] = 0.f;

  for (int k0 = 0; k0 < D; k0 += 16) {
    {
      int r = tid >> 2, f = tid & 3;
      *(float4*)(&As[r][f * 4]) = *(const float4*)(&qn[(m0 + r) * D + k0 + f * 4]);
    }
#pragma unroll
    for (int i = 0; i < 8; i++) {
      int r = (tid >> 2) + 64 * i, f = tid & 3;
      int gr = n0 + r;
      float4 v = make_float4(0.f, 0.f, 0.f, 0.f);
      if (gr < NKEYS) v = *(const float4*)(&keys[(long long)gr * D + k0 + f * 4]);
      *(float4*)(&Bs[r][f * 4]) = v;
    }
    __syncthreads();
#pragma unroll
    for (int kk = 0; kk < 16; kk += 4) {
      float4 af[8];
#pragma unroll
      for (int i = 0; i < 8; i++) af[i] = *(const float4*)(&As[qt * 8 + i][kk]);
#pragma unroll
      for (int j = 0; j < 16; j++) {
        float4 bf = *(const float4*)(&Bs[nt + 32 * j][kk]);
#pragma unroll
        for (int i = 0; i < 8; i++) {
          acc[i][j] = fmaf(af[i].x, bf.x, acc[i][j]);
          acc[i][j] = fmaf(af[i].y, bf.y, acc[i][j]);
          acc[i][j] = fmaf(af[i].z, bf.z, acc[i][j]);
          acc[i][j] = fmaf(af[i].w, bf.w, acc[i][j]);
        }
      }
    }
    __syncthreads();
  }

  int cols[16];
  float inv[16];
#pragma unroll
  for (int j = 0; j < 16; j++) {
    int c = n0 + nt + 32 * j;
    cols[j] = c;
    inv[j] = (c < NKEYS) ? kinvf[c] : 0.f;
  }
#pragma unroll
  for (int i = 0; i < 8; i++)
#pragma unroll
    for (int j = 0; j < 16; j++)
      acc[i][j] = (cols[j] < NKEYS) ? acc[i][j] * inv[j] : NEG_INF;

#pragma unroll
  for (int i = 0; i < 8; i++) {
    int row = m0 + qt * 8 + i;
    int base = row * (NCHUNK * 8) + blockIdx.x * 8;
#pragma unroll 1
    for (int r = 0; r < 8; r++) {
      float bv = NEG_INF;
      int bi = 0x7fffffff;
#pragma unroll
      for (int j = 0; j < 16; j++) {
        if (acc[i][j] > bv || (acc[i][j] == bv && cols[j] < bi)) { bv = acc[i][j]; bi = cols[j]; }
      }
#pragma unroll
      for (int m = 16; m; m >>= 1) {
        float ov = __shfl_xor(bv, m, 32);
        int oi = __shfl_xor(bi, m, 32);
        if (ov > bv || (ov == bv && oi < bi)) { bv = ov; bi = oi; }
      }
      if (nt == r) { cand_s[base + r] = bv; cand_i[base + r] = bi; }
#pragma unroll
      for (int j = 0; j < 16; j++)
        if (cols[j] == bi) acc[i][j] = NEG_INF;
    }
  }
}

// ---------- Kernel 5: merge candidates -> fp32 top-16 indices ----------
__global__ __launch_bounds__(256) void merge_kernel(const float* __restrict__ cand_s,
                                                    const int* __restrict__ cand_i,
                                                    int* __restrict__ fidx16) {
  const int q = blockIdx.x;
  const int tid = threadIdx.x;
  const int NC = NCHUNK * 8;  // 784
  float lv[4];
  int li[4];
#pragma unroll
  for (int s = 0; s < 4; s++) {
    int c = tid + 256 * s;
    if (c < NC) { lv[s] = cand_s[q * NC + c]; li[s] = cand_i[q * NC + c]; }
    else        { lv[s] = NEG_INF; li[s] = 0x7fffffff; }
  }
  __shared__ float swv[4];
  __shared__ int   swi[4];
  __shared__ float wvs;
  __shared__ int   wis;
  int wave = tid >> 6, lane = tid & 63;
#pragma unroll 1
  for (int r = 0; r < NCAND; r++) {
    float bv = NEG_INF;
    int bi = 0x7fffffff;
#pragma unroll
    for (int s = 0; s < 4; s++)
      if (lv[s] > bv || (lv[s] == bv && li[s] < bi)) { bv = lv[s]; bi = li[s]; }
#pragma unroll
    for (int m = 32; m; m >>= 1) {
      float ov = __shfl_xor(bv, m, 64);
      int oi = __shfl_xor(bi, m, 64);
      if (ov > bv || (ov == bv && oi < bi)) { bv = ov; bi = oi; }
    }
    if (lane == 0) { swv[wave] = bv; swi[wave] = bi; }
    __syncthreads();
    if (tid == 0) {
      float fv = swv[0];
      int fi = swi[0];
#pragma unroll
      for (int w = 1; w < 4; w++)
        if (swv[w] > fv || (swv[w] == fv && swi[w] < fi)) { fv = swv[w]; fi = swi[w]; }
      wvs = fv; wis = fi;
    }
    __syncthreads();
    int fi = wis;
    if (tid == r) fidx16[q * NCAND + r] = fi;
#pragma unroll
    for (int s = 0; s < 4; s++)
      if (li[s] == fi) lv[s] = NEG_INF;
  }
}

// ---------- Kernel 6: fp64 exact rescore of 16 candidates -> final top-8 ----------
__global__ __launch_bounds__(256) void rescore_kernel(const double* __restrict__ q64n,
                                                      const float* __restrict__ keys,
                                                      const double* __restrict__ kinv64,
                                                      const int* __restrict__ fidx16,
                                                      float* __restrict__ scores_out,
                                                      int* __restrict__ fidx8,
                                                      float* __restrict__ usage_out) {
  const int q = blockIdx.x;
  const int tid = threadIdx.x;
  const int g = tid >> 4, l = tid & 15;
  const int idx = fidx16[q * NCAND + g];

  double s = 0.0;
  const double* qrow = &q64n[(long long)q * D + l * 16];
  const float* krow = &keys[(long long)idx * D + l * 16];
#pragma unroll
  for (int t = 0; t < 16; t++) s = fma(qrow[t], (double)krow[t], s);
#pragma unroll
  for (int m = 8; m; m >>= 1) s += __shfl_xor(s, m, 16);

  __shared__ double sc[NCAND];
  __shared__ int    si[NCAND];
  __shared__ double s8[8];
  __shared__ int    f8[8];
  if (l == 0) { sc[g] = s * kinv64[idx]; si[g] = idx; }
  __syncthreads();
  if (tid == 0) {
#pragma unroll 1
    for (int r = 0; r < 8; r++) {
      double bv = DNEG_INF;
      int bi = 0x7fffffff, bg = -1;
#pragma unroll
      for (int t = 0; t < NCAND; t++) {
        if (sc[t] > bv || (sc[t] == bv && si[t] < bi)) { bv = sc[t]; bi = si[t]; bg = t; }
      }
      s8[r] = bv; f8[r] = bi;
      sc[bg] = DNEG_INF;
    }
  }
  __syncthreads();
  if (tid < 8) {
    scores_out[q * 8 + tid] = (float)s8[tid];
    fidx8[q * 8 + tid] = f8[tid];
    atomicAdd(&usage_out[f8[tid]], 1.0f);
  }
}

// ---------- Kernel 7: gather retrieved values ----------
__global__ __launch_bounds__(256) void gather_kernel(const float* __restrict__ values,
                                                     const int* __restrict__ fidx8,
                                                     float* __restrict__ out_rv) {
  int wave = threadIdx.x >> 6, lane = threadIdx.x & 63;
  int row = blockIdx.x * 4 + wave;  // q*8+rank
  int idx = fidx8[row];
  float4 v = *(const float4*)(&values[(long long)idx * D + lane * 4]);
  *(float4*)(&out_rv[(long long)row * D + lane * 4]) = v;
}

extern "C" void kernel_launch(void* const* d_in, const int* in_sizes, int n_in,
                              void* d_out, int out_size, void* d_ws, size_t ws_size,
                              hipStream_t stream) {
  (void)in_sizes; (void)n_in; (void)out_size; (void)ws_size;
  const float* query  = (const float*)d_in[0];
  const float* W      = (const float*)d_in[1];
  const float* b      = (const float*)d_in[2];
  const float* keys   = (const float*)d_in[3];
  const float* values = (const float*)d_in[4];
  const float* usage  = (const float*)d_in[5];

  float* out    = (float*)d_out;
  float* out_rv = out;                    // 2048*8*256
  float* out_sc = out + BQ * 8 * D;       // 2048*8
  float* out_us = out_sc + BQ * 8;        // 50000

  // workspace layout (doubles first for 8B alignment)
  double* q64n   = (double*)d_ws;                   // 524288 d
  double* kinv64 = q64n + BQ * D;                   // 50000 d
  float*  qn     = (float*)(kinv64 + NKEYS);        // 524288 f
  float*  kinvf  = qn + BQ * D;                     // 50000 f
  float*  cand_s = kinvf + NKEYS;                   // 2048*784 f
  int*    cand_i = (int*)(cand_s + BQ * NCHUNK * 8);// 2048*784 i
  int*    fidx16 = cand_i + BQ * NCHUNK * 8;        // 2048*16 i
  int*    fidx8  = fidx16 + BQ * NCAND;             // 2048*8 i

  hipLaunchKernelGGL(qnorm_kernel, dim3(BQ / 32), dim3(256), 0, stream, query, W, b, qn, q64n);
  hipLaunchKernelGGL(knorm_kernel, dim3(NKEYS / 4 + 1), dim3(256), 0, stream, keys, kinvf, kinv64);
  hipLaunchKernelGGL(usage_copy_kernel, dim3((NKEYS + 255) / 256), dim3(256), 0, stream, usage, out_us);
  hipLaunchKernelGGL(sim_topk_kernel, dim3(NCHUNK, BQ / 64), dim3(256), 0, stream, qn, keys, kinvf, cand_s, cand_i);
  hipLaunchKernelGGL(merge_kernel, dim3(BQ), dim3(256), 0, stream, cand_s, cand_i, fidx16);
  hipLaunchKernelGGL(rescore_kernel, dim3(BQ), dim3(256), 0, stream, q64n, keys, kinv64, fidx16, out_sc, fidx8, out_us);
  hipLaunchKernelGGL(gather_kernel, dim3(BQ * 8 / 4), dim3(256), 0, stream, values, fidx8, out_rv);
}

// Round 4
// 521.740 us; speedup vs baseline: 6.0087x; 4.7422x over previous
//
#include <hip/hip_runtime.h>

#define D 256
#define NKEYS 50000
#define NKPAD 50176          // 98*512
#define BQ 2048
#define NT_SIM 512
#define NCHUNK 98            // ceil(50000/512)
#define NCAND 24             // rescored candidates per query
#define NEG_INF (-3.402823466e38f)
#define DNEG_INF (-1.0e300)

typedef __attribute__((ext_vector_type(8))) __bf16 bf16x8;
typedef __attribute__((ext_vector_type(4))) float floatx4;

// round-to-nearest-even f32 -> bf16 bits
__device__ __forceinline__ unsigned short f2bf(float x) {
  unsigned int u = __float_as_uint(x);
  unsigned int r = (u + 0x7fffu + ((u >> 16) & 1u)) >> 16;
  return (unsigned short)r;
}

// ---------- Kernel 1: q = query @ W^T + b (fp64 accum), L2-normalize ----------
// Writes fp64 normalized q (rescore path) and bf16 normalized q (MFMA path, plain layout).
__global__ __launch_bounds__(256) void qnorm_kernel(const float* __restrict__ query,
                                                    const float* __restrict__ W,
                                                    const float* __restrict__ b,
                                                    unsigned short* __restrict__ qbf,
                                                    double* __restrict__ q64n) {
  __shared__ __align__(16) float As[32][20];
  __shared__ __align__(16) float Bs[256][20];
  const int tid = threadIdx.x;
  const int qt = tid >> 5;   // 0..7 -> rows qt*4+i
  const int nt = tid & 31;   // cols nt + 32*j, j<8
  const int m0 = blockIdx.x * 32;

  double acc[4][8];
#pragma unroll
  for (int i = 0; i < 4; i++)
#pragma unroll
    for (int j = 0; j < 8; j++) acc[i][j] = 0.0;

  for (int k0 = 0; k0 < D; k0 += 16) {
    if (tid < 128) {
      int r = tid >> 2, f = tid & 3;
      *(float4*)(&As[r][f * 4]) = *(const float4*)(&query[(m0 + r) * D + k0 + f * 4]);
    }
#pragma unroll
    for (int i = 0; i < 4; i++) {
      int r = (tid >> 2) + 64 * i, f = tid & 3;
      *(float4*)(&Bs[r][f * 4]) = *(const float4*)(&W[r * D + k0 + f * 4]);
    }
    __syncthreads();
#pragma unroll
    for (int kk = 0; kk < 16; kk += 4) {
      float4 af[4];
#pragma unroll
      for (int i = 0; i < 4; i++) af[i] = *(const float4*)(&As[qt * 4 + i][kk]);
#pragma unroll
      for (int j = 0; j < 8; j++) {
        float4 bf = *(const float4*)(&Bs[nt + 32 * j][kk]);
#pragma unroll
        for (int i = 0; i < 4; i++) {
          acc[i][j] = fma((double)af[i].x, (double)bf.x, acc[i][j]);
          acc[i][j] = fma((double)af[i].y, (double)bf.y, acc[i][j]);
          acc[i][j] = fma((double)af[i].z, (double)bf.z, acc[i][j]);
          acc[i][j] = fma((double)af[i].w, (double)bf.w, acc[i][j]);
        }
      }
    }
    __syncthreads();
  }
#pragma unroll
  for (int i = 0; i < 4; i++)
#pragma unroll
    for (int j = 0; j < 8; j++) acc[i][j] += (double)b[nt + 32 * j];

#pragma unroll
  for (int i = 0; i < 4; i++) {
    double s = 0.0;
#pragma unroll
    for (int j = 0; j < 8; j++) s = fma(acc[i][j], acc[i][j], s);
#pragma unroll
    for (int m = 16; m; m >>= 1) s += __shfl_xor(s, m, 32);
    double den = fmax(sqrt(s), 1e-12);
    int row = m0 + qt * 4 + i;
#pragma unroll
    for (int j = 0; j < 8; j++) {
      double v = acc[i][j] / den;
      q64n[row * D + nt + 32 * j] = v;
      qbf[row * D + nt + 32 * j] = f2bf((float)v);
    }
  }
}

// ---------- Kernel 2: key prep: fp64 inv-norm + normalized bf16 keys, pre-swizzled ----------
// kbf layout: row r (512B): 4 phase-blocks of 128B (64 elems); within block, elem
// position e' = e ^ ((r&7)<<3)  (byte XOR ((r&7)<<4)) so that linear global_load_lds
// lands the T2-swizzled tile in LDS. Rows >= NKEYS are zero-filled.
__global__ __launch_bounds__(256) void kprep_kernel(const float* __restrict__ keys,
                                                    double* __restrict__ kinv64,
                                                    unsigned short* __restrict__ kbf) {
  int wave = threadIdx.x >> 6, lane = threadIdx.x & 63;
  int r = blockIdx.x * 4 + wave;
  if (r >= NKPAD) return;
  int c = lane * 4;                 // 4 consecutive elems
  int pb = c >> 6;                  // phase block
  int e = c & 63;
  int e2 = e ^ ((r & 7) << 3);      // swizzled elem within block
  unsigned short* dst = kbf + (long long)r * D + pb * 64 + e2;
  if (r >= NKEYS) {
    ushort4 z = {0, 0, 0, 0};
    *(ushort4*)dst = z;
    return;
  }
  float4 v = *(const float4*)(&keys[(long long)r * D + c]);
  double s = (double)v.x * v.x + (double)v.y * v.y + (double)v.z * v.z + (double)v.w * v.w;
#pragma unroll
  for (int m = 32; m; m >>= 1) s += __shfl_xor(s, m, 64);
  double inv = 1.0 / fmax(sqrt(s), 1e-12);
  if (lane == 0) kinv64[r] = inv;
  float fi = (float)inv;
  ushort4 o;
  o.x = f2bf(v.x * fi); o.y = f2bf(v.y * fi); o.z = f2bf(v.z * fi); o.w = f2bf(v.w * fi);
  *(ushort4*)dst = o;
}

// ---------- Kernel 3: usage copy ----------
__global__ void usage_copy_kernel(const float* __restrict__ usage, float* __restrict__ out_u) {
  int i = blockIdx.x * 256 + threadIdx.x;
  if (i < NKEYS) out_u[i] = usage[i];
}

// ---------- Kernel 4: bf16 MFMA sim + fused per-chunk top-8 ----------
// Block: 4 waves, 64 queries x 512 keys. Wave w owns queries m0+16w..+16.
// C[key][query] orientation: per MFMA, col=lane&15=query, row=(lane>>4)*4+reg=key-sub.
__global__ __launch_bounds__(256, 1) void sim_mfma_kernel(const unsigned short* __restrict__ qbf,
                                                          const unsigned short* __restrict__ kbf,
                                                          float* __restrict__ cand_s,
                                                          int* __restrict__ cand_i) {
  __shared__ __align__(16) unsigned char klds[512 * 128];  // 64KB: [512 keys][128B = 64 k-elems]
  const int tid = threadIdx.x;
  const int w = tid >> 6;
  const int l = tid & 63;
  const int g = l >> 4;            // lane group 0..3
  const int n0 = blockIdx.x * NT_SIM;
  const int m0 = blockIdx.y * 64;
  const int qrow = m0 + w * 16 + (l & 15);

  // resident q fragments: j = p*2+h covers k = j*32 + g*8 .. +8
  bf16x8 qf[8];
#pragma unroll
  for (int j = 0; j < 8; j++)
    qf[j] = *(const bf16x8*)(qbf + (long long)qrow * D + j * 32 + g * 8);

  floatx4 acc[32];
#pragma unroll
  for (int t = 0; t < 32; t++) acc[t] = (floatx4){0.f, 0.f, 0.f, 0.f};

#pragma unroll
  for (int p = 0; p < 4; p++) {
    __syncthreads();   // prior compute done before overwrite
    // stage 64KB of this chunk's keys (phase p: 64 k-elems/row), linear LDS dest,
    // swizzle pre-baked in kbf global layout.
#pragma unroll
    for (int i = 0; i < 16; i++) {
      int dstbase = (i * 4 + w) * 1024;
      int off = dstbase + l * 16;
      int r_loc = off >> 7;
      int bir = off & 127;
      const void* src = (const char*)kbf + ((long long)(n0 + r_loc) * 512 + p * 128 + bir);
      __builtin_amdgcn_global_load_lds(src, (void*)(klds + dstbase), 16, 0, 0);
    }
    __syncthreads();   // drains vmcnt before barrier
#pragma unroll
    for (int t = 0; t < 32; t++) {
      int r0 = t * 16 + (l & 15);
      int swz = (r0 & 7) << 4;
      int byte0 = r0 * 128 + g * 16;
      bf16x8 a0 = *(const bf16x8*)(klds + ((byte0) ^ swz));
      bf16x8 a1 = *(const bf16x8*)(klds + ((byte0 + 64) ^ swz));
      acc[t] = __builtin_amdgcn_mfma_f32_16x16x32_bf16(a0, qf[p * 2], acc[t], 0, 0, 0);
      acc[t] = __builtin_amdgcn_mfma_f32_16x16x32_bf16(a1, qf[p * 2 + 1], acc[t], 0, 0, 0);
    }
  }

  // mask invalid keys (last chunk only; uniform branch)
  if (n0 + NT_SIM > NKEYS) {
#pragma unroll
    for (int t = 0; t < 32; t++)
#pragma unroll
      for (int r = 0; r < 4; r++) {
        int key = n0 + t * 16 + g * 4 + r;
        if (key >= NKEYS) acc[t][r] = NEG_INF;
      }
  }

  // per-chunk top-8 per query: thread-local argmax over 128 + quad merge (xor 16,32).
  // slot s -> key = n0 + (s>>2)*16 + g*4 + (s&3)  (monotone in s => first-win = smallest key)
  const int base = qrow * (NCHUNK * 8) + blockIdx.x * 8;
#pragma unroll 1
  for (int r = 0; r < 8; r++) {
    float bv = NEG_INF;
    int bs = 0;
#pragma unroll
    for (int s = 0; s < 128; s++) {
      float v = acc[s >> 2][s & 3];
      if (v > bv) { bv = v; bs = s; }
    }
    int bkey = n0 + ((bs >> 2) << 4) + g * 4 + (bs & 3);
#pragma unroll
    for (int m = 16; m <= 32; m <<= 1) {
      float ov = __shfl_xor(bv, m, 64);
      int ok = __shfl_xor(bkey, m, 64);
      if (ov > bv || (ov == bv && ok < bkey)) { bv = ov; bkey = ok; }
    }
    if (g == 0) { cand_s[base + r] = bv; cand_i[base + r] = bkey; }
    // invalidate winner in its owner lane
    int kk = bkey - n0;
    if (((kk >> 2) & 3) == g) {
      int oslot = ((kk >> 4) << 2) | (kk & 3);
#pragma unroll
      for (int s = 0; s < 128; s++)
        if (s == oslot) acc[s >> 2][s & 3] = NEG_INF;
    }
  }
}

// ---------- Kernel 5: merge candidates -> bf16-score top-24 indices ----------
__global__ __launch_bounds__(256) void merge_kernel(const float* __restrict__ cand_s,
                                                    const int* __restrict__ cand_i,
                                                    int* __restrict__ fidx24) {
  const int q = blockIdx.x;
  const int tid = threadIdx.x;
  const int NC = NCHUNK * 8;  // 784
  float lv[4];
  int li[4];
#pragma unroll
  for (int s = 0; s < 4; s++) {
    int c = tid + 256 * s;
    if (c < NC) { lv[s] = cand_s[q * NC + c]; li[s] = cand_i[q * NC + c]; }
    else        { lv[s] = NEG_INF; li[s] = 0x7fffffff; }
  }
  __shared__ float swv[4];
  __shared__ int   swi[4];
  __shared__ float wvs;
  __shared__ int   wis;
  int wave = tid >> 6, lane = tid & 63;
#pragma unroll 1
  for (int r = 0; r < NCAND; r++) {
    float bv = NEG_INF;
    int bi = 0x7fffffff;
#pragma unroll
    for (int s = 0; s < 4; s++)
      if (lv[s] > bv || (lv[s] == bv && li[s] < bi)) { bv = lv[s]; bi = li[s]; }
#pragma unroll
    for (int m = 32; m; m >>= 1) {
      float ov = __shfl_xor(bv, m, 64);
      int oi = __shfl_xor(bi, m, 64);
      if (ov > bv || (ov == bv && oi < bi)) { bv = ov; bi = oi; }
    }
    if (lane == 0) { swv[wave] = bv; swi[wave] = bi; }
    __syncthreads();
    if (tid == 0) {
      float fv = swv[0];
      int fi = swi[0];
#pragma unroll
      for (int t = 1; t < 4; t++)
        if (swv[t] > fv || (swv[t] == fv && swi[t] < fi)) { fv = swv[t]; fi = swi[t]; }
      wvs = fv; wis = fi;
    }
    __syncthreads();
    int fi = wis;
    if (tid == r) fidx24[q * NCAND + r] = fi;
#pragma unroll
    for (int s = 0; s < 4; s++)
      if (li[s] == fi) lv[s] = NEG_INF;
  }
}

// ---------- Kernel 6: fp64 exact rescore of 24 candidates -> final top-8 ----------
// group g=tid>>3 (24 used) handles one candidate; lane l=tid&7 handles 32 dims.
__global__ __launch_bounds__(256) void rescore_kernel(const double* __restrict__ q64n,
                                                      const float* __restrict__ keys,
                                                      const double* __restrict__ kinv64,
                                                      const int* __restrict__ fidx24,
                                                      float* __restrict__ scores_out,
                                                      int* __restrict__ fidx8,
                                                      float* __restrict__ usage_out) {
  const int q = blockIdx.x;
  const int tid = threadIdx.x;
  const int g = tid >> 3, l = tid & 7;
  __shared__ double sc[NCAND];
  __shared__ int    si[NCAND];
  __shared__ double s8[8];
  __shared__ int    f8[8];
  if (g < NCAND) {
    int idx = fidx24[q * NCAND + g];
    double s = 0.0;
    const double* qrow = &q64n[(long long)q * D + l * 32];
    const float* krow = &keys[(long long)idx * D + l * 32];
#pragma unroll
    for (int t = 0; t < 32; t++) s = fma(qrow[t], (double)krow[t], s);
#pragma unroll
    for (int m = 4; m; m >>= 1) s += __shfl_xor(s, m, 8);
    if (l == 0) { sc[g] = s * kinv64[idx]; si[g] = idx; }
  }
  __syncthreads();
  if (tid == 0) {
#pragma unroll 1
    for (int r = 0; r < 8; r++) {
      double bv = DNEG_INF;
      int bi = 0x7fffffff, bg = -1;
#pragma unroll
      for (int t = 0; t < NCAND; t++) {
        if (sc[t] > bv || (sc[t] == bv && si[t] < bi)) { bv = sc[t]; bi = si[t]; bg = t; }
      }
      s8[r] = bv; f8[r] = bi;
      sc[bg] = DNEG_INF;
    }
  }
  __syncthreads();
  if (tid < 8) {
    scores_out[q * 8 + tid] = (float)s8[tid];
    fidx8[q * 8 + tid] = f8[tid];
    atomicAdd(&usage_out[f8[tid]], 1.0f);
  }
}

// ---------- Kernel 7: gather retrieved values ----------
__global__ __launch_bounds__(256) void gather_kernel(const float* __restrict__ values,
                                                     const int* __restrict__ fidx8,
                                                     float* __restrict__ out_rv) {
  int wave = threadIdx.x >> 6, lane = threadIdx.x & 63;
  int row = blockIdx.x * 4 + wave;  // q*8+rank
  int idx = fidx8[row];
  float4 v = *(const float4*)(&values[(long long)idx * D + lane * 4]);
  *(float4*)(&out_rv[(long long)row * D + lane * 4]) = v;
}

extern "C" void kernel_launch(void* const* d_in, const int* in_sizes, int n_in,
                              void* d_out, int out_size, void* d_ws, size_t ws_size,
                              hipStream_t stream) {
  (void)in_sizes; (void)n_in; (void)out_size; (void)ws_size;
  const float* query  = (const float*)d_in[0];
  const float* W      = (const float*)d_in[1];
  const float* b      = (const float*)d_in[2];
  const float* keys   = (const float*)d_in[3];
  const float* values = (const float*)d_in[4];
  const float* usage  = (const float*)d_in[5];

  float* out    = (float*)d_out;
  float* out_rv = out;                    // 2048*8*256
  float* out_sc = out + BQ * 8 * D;       // 2048*8
  float* out_us = out_sc + BQ * 8;        // 50000

  // workspace layout (8B-aligned first)
  double*         q64n   = (double*)d_ws;                    // 524288 d   (4.0MB)
  double*         kinv64 = q64n + BQ * D;                    // 50000 d    (0.4MB)
  unsigned short* qbf    = (unsigned short*)(kinv64 + NKEYS);// 524288 us  (1.0MB)
  unsigned short* kbf    = qbf + BQ * D;                     // 50176*256  (25.7MB)
  float*          cand_s = (float*)(kbf + (long long)NKPAD * D);   // 2048*784 f
  int*            cand_i = (int*)(cand_s + BQ * NCHUNK * 8);       // 2048*784 i
  int*            fidx24 = cand_i + BQ * NCHUNK * 8;               // 2048*24 i
  int*            fidx8  = fidx24 + BQ * NCAND;                    // 2048*8 i

  hipLaunchKernelGGL(qnorm_kernel, dim3(BQ / 32), dim3(256), 0, stream, query, W, b, qbf, q64n);
  hipLaunchKernelGGL(kprep_kernel, dim3(NKPAD / 4), dim3(256), 0, stream, keys, kinv64, kbf);
  hipLaunchKernelGGL(usage_copy_kernel, dim3((NKEYS + 255) / 256), dim3(256), 0, stream, usage, out_us);
  hipLaunchKernelGGL(sim_mfma_kernel, dim3(NCHUNK, BQ / 64), dim3(256), 0, stream, qbf, kbf, cand_s, cand_i);
  hipLaunchKernelGGL(merge_kernel, dim3(BQ), dim3(256), 0, stream, cand_s, cand_i, fidx24);
  hipLaunchKernelGGL(rescore_kernel, dim3(BQ), dim3(256), 0, stream, q64n, keys, kinv64, fidx24, out_sc, fidx8, out_us);
  hipLaunchKernelGGL(gather_kernel, dim3(BQ * 8 / 4), dim3(256), 0, stream, values, fidx8, out_rv);
}

// Round 5
// 411.455 us; speedup vs baseline: 7.6193x; 1.2680x over previous
//
#include <hip/hip_runtime.h>

#define D 256
#define NKEYS 50000
#define KCHUNK 256
#define NCHUNK 196           // 50176 / 256
#define NKPAD (KCHUNK * NCHUNK)
#define BQ 2048
#define NC (NCHUNK * 8)      // 1568 candidates/query
#define NCAND 24             // rescored candidates per query
#define DNEG_INF (-1.0e300)

typedef __attribute__((ext_vector_type(8))) __bf16 bf16x8;
typedef __attribute__((ext_vector_type(16))) float f32x16;

// round-to-nearest-even f32 -> bf16 bits
__device__ __forceinline__ unsigned short f2bf(float x) {
  unsigned int u = __float_as_uint(x);
  unsigned int r = (u + 0x7fffu + ((u >> 16) & 1u)) >> 16;
  return (unsigned short)r;
}

// ---------- Kernel 1: q = query @ W^T + b (fp64 accum), L2-normalize ----------
__global__ __launch_bounds__(256) void qnorm_kernel(const float* __restrict__ query,
                                                    const float* __restrict__ W,
                                                    const float* __restrict__ b,
                                                    unsigned short* __restrict__ qbf,
                                                    double* __restrict__ q64n) {
  __shared__ __align__(16) float As[32][20];
  __shared__ __align__(16) float Bs[256][20];
  const int tid = threadIdx.x;
  const int qt = tid >> 5;
  const int nt = tid & 31;
  const int m0 = blockIdx.x * 32;

  double acc[4][8];
#pragma unroll
  for (int i = 0; i < 4; i++)
#pragma unroll
    for (int j = 0; j < 8; j++) acc[i][j] = 0.0;

  for (int k0 = 0; k0 < D; k0 += 16) {
    if (tid < 128) {
      int r = tid >> 2, f = tid & 3;
      *(float4*)(&As[r][f * 4]) = *(const float4*)(&query[(m0 + r) * D + k0 + f * 4]);
    }
#pragma unroll
    for (int i = 0; i < 4; i++) {
      int r = (tid >> 2) + 64 * i, f = tid & 3;
      *(float4*)(&Bs[r][f * 4]) = *(const float4*)(&W[r * D + k0 + f * 4]);
    }
    __syncthreads();
#pragma unroll
    for (int kk = 0; kk < 16; kk += 4) {
      float4 af[4];
#pragma unroll
      for (int i = 0; i < 4; i++) af[i] = *(const float4*)(&As[qt * 4 + i][kk]);
#pragma unroll
      for (int j = 0; j < 8; j++) {
        float4 bf = *(const float4*)(&Bs[nt + 32 * j][kk]);
#pragma unroll
        for (int i = 0; i < 4; i++) {
          acc[i][j] = fma((double)af[i].x, (double)bf.x, acc[i][j]);
          acc[i][j] = fma((double)af[i].y, (double)bf.y, acc[i][j]);
          acc[i][j] = fma((double)af[i].z, (double)bf.z, acc[i][j]);
          acc[i][j] = fma((double)af[i].w, (double)bf.w, acc[i][j]);
        }
      }
    }
    __syncthreads();
  }
#pragma unroll
  for (int i = 0; i < 4; i++)
#pragma unroll
    for (int j = 0; j < 8; j++) acc[i][j] += (double)b[nt + 32 * j];

#pragma unroll
  for (int i = 0; i < 4; i++) {
    double s = 0.0;
#pragma unroll
    for (int j = 0; j < 8; j++) s = fma(acc[i][j], acc[i][j], s);
#pragma unroll
    for (int m = 16; m; m >>= 1) s += __shfl_xor(s, m, 32);
    double den = fmax(sqrt(s), 1e-12);
    int row = m0 + qt * 4 + i;
#pragma unroll
    for (int j = 0; j < 8; j++) {
      double v = acc[i][j] / den;
      q64n[row * D + nt + 32 * j] = v;
      qbf[row * D + nt + 32 * j] = f2bf((float)v);
    }
  }
}

// ---------- Kernel 2: key prep: fp64 inv-norm + normalized bf16 keys, pre-swizzled ----------
// kbf row r (512B): 4 phase-blocks of 128B; within block elem e' = e ^ ((r&7)<<3).
__global__ __launch_bounds__(256) void kprep_kernel(const float* __restrict__ keys,
                                                    double* __restrict__ kinv64,
                                                    unsigned short* __restrict__ kbf) {
  int wave = threadIdx.x >> 6, lane = threadIdx.x & 63;
  int r = blockIdx.x * 4 + wave;
  if (r >= NKPAD) return;
  int c = lane * 4;
  int pb = c >> 6;
  int e = c & 63;
  int e2 = e ^ ((r & 7) << 3);
  unsigned short* dst = kbf + (long long)r * D + pb * 64 + e2;
  if (r >= NKEYS) {
    ushort4 z = {0, 0, 0, 0};
    *(ushort4*)dst = z;
    return;
  }
  float4 v = *(const float4*)(&keys[(long long)r * D + c]);
  double s = (double)v.x * v.x + (double)v.y * v.y + (double)v.z * v.z + (double)v.w * v.w;
#pragma unroll
  for (int m = 32; m; m >>= 1) s += __shfl_xor(s, m, 64);
  double inv = 1.0 / fmax(sqrt(s), 1e-12);
  if (lane == 0) kinv64[r] = inv;
  float fi = (float)inv;
  ushort4 o;
  o.x = f2bf(v.x * fi); o.y = f2bf(v.y * fi); o.z = f2bf(v.z * fi); o.w = f2bf(v.w * fi);
  *(ushort4*)dst = o;
}

// ---------- Kernel 3: usage copy ----------
__global__ void usage_copy_kernel(const float* __restrict__ usage, float* __restrict__ out_u) {
  int i = blockIdx.x * 256 + threadIdx.x;
  if (i < NKEYS) out_u[i] = usage[i];
}

// ---------- Kernel 4: 32x32x16 bf16 MFMA sim + packed-u32 per-chunk top-8 ----------
// Block: 4 waves, 128 queries x 256 keys. Wave w: queries m0+w*32+ (lane&31).
// acc tile t: keys n0+t*32.., C row=(reg&3)+8*(reg>>2)+4*(lane>>5), col=lane&31.
__global__ __launch_bounds__(256, 1) void sim_mfma_kernel(const unsigned short* __restrict__ qbf,
                                                          const unsigned short* __restrict__ kbf,
                                                          unsigned int* __restrict__ cand_p) {
  __shared__ __align__(16) unsigned char klds[KCHUNK * 128];  // 32KB
  const int tid = threadIdx.x;
  const int w = tid >> 6;
  const int l = tid & 63;
  const int col = l & 31;
  const int hi = l >> 5;
  const int n0 = blockIdx.x * KCHUNK;
  const int m0 = blockIdx.y * 128;
  const int qrow = m0 + w * 32 + col;

  // B fragments (queries) resident: kstep ks covers k = ks*16 + hi*8 .. +8
  bf16x8 qf[16];
#pragma unroll
  for (int ks = 0; ks < 16; ks++)
    qf[ks] = *(const bf16x8*)(qbf + (long long)qrow * D + ks * 16 + hi * 8);

  f32x16 acc[8];
#pragma unroll
  for (int t = 0; t < 8; t++)
#pragma unroll
    for (int r = 0; r < 16; r++) acc[t][r] = 0.f;

  const int swz = (l & 7) << 4;
#pragma unroll
  for (int p = 0; p < 4; p++) {
    __syncthreads();
    // stage 32KB: 256 keys x 128B (phase p), linear LDS, swizzle pre-baked in kbf
#pragma unroll
    for (int i = 0; i < 8; i++) {
      int dstbase = (i * 4 + w) * 1024;
      int off = dstbase + l * 16;
      int r_loc = off >> 7;
      const void* src = (const char*)kbf + ((long long)(n0 + r_loc) * 512 + p * 128 + (off & 127));
      __builtin_amdgcn_global_load_lds(src, (void*)(klds + dstbase), 16, 0, 0);
    }
    __syncthreads();
#pragma unroll
    for (int t = 0; t < 8; t++) {
      int rowbase = (t * 32 + col) * 128 + hi * 16;
#pragma unroll
      for (int s = 0; s < 4; s++) {
        bf16x8 a = *(const bf16x8*)(klds + ((rowbase + s * 32) ^ swz));
        acc[t] = __builtin_amdgcn_mfma_f32_32x32x16_bf16(a, qf[p * 4 + s], acc[t], 0, 0, 0);
      }
    }
  }

  // pack scores -> monotone u32 with slot id in low 8 bits; mask invalid keys to 0
  unsigned int pk[8][16];
  const bool edge = (n0 + KCHUNK > NKEYS);
#pragma unroll
  for (int t = 0; t < 8; t++)
#pragma unroll
    for (int r = 0; r < 16; r++) {
      unsigned int m = __float_as_uint(acc[t][r]);
      unsigned int u = (m & 0x80000000u) ? ~m : (m | 0x80000000u);
      unsigned int v = (u & 0xFFFFFF00u) | (unsigned)(((t * 16 + r) << 1) | hi);
      if (edge) {
        int key = n0 + t * 32 + (r & 3) + 8 * (r >> 2) + 4 * hi;
        if (key >= NKEYS) v = 0u;
      }
      pk[t][r] = v;
    }

  // 8 rounds: umax-reduce 128 regs, merge across lane pair (hi), invalidate
  const long long base = (long long)qrow * NC + blockIdx.x * 8;
#pragma unroll 1
  for (int r = 0; r < 8; r++) {
    unsigned int wv = 0u;
#pragma unroll
    for (int t = 0; t < 8; t++)
#pragma unroll
      for (int s = 0; s < 16; s++) wv = max(wv, pk[t][s]);
    unsigned int ov = (unsigned int)__shfl_xor((int)wv, 32, 64);
    unsigned int wm = max(wv, ov);
    if (hi == 0) cand_p[base + r] = wm;
#pragma unroll
    for (int t = 0; t < 8; t++)
#pragma unroll
      for (int s = 0; s < 16; s++) pk[t][s] = (pk[t][s] == wm) ? 0u : pk[t][s];
  }
}

// ---------- Kernel 5: merge 1568 candidates -> top-24 (one wave per query) ----------
__global__ __launch_bounds__(256) void merge_kernel(const unsigned int* __restrict__ cand_p,
                                                    int* __restrict__ fidx24) {
  const int q = blockIdx.x * 4 + (threadIdx.x >> 6);
  const int lane = threadIdx.x & 63;
  unsigned int lv[25];
  int li[25];
#pragma unroll
  for (int s = 0; s < 25; s++) {
    int c = lane + 64 * s;
    if (c < NC) {
      unsigned int p = cand_p[(long long)q * NC + c];
      int sl = p & 255;
      int hh = sl & 1, ss = sl >> 1, t = ss >> 4, rg = ss & 15;
      lv[s] = p;
      li[s] = (c >> 3) * KCHUNK + t * 32 + (rg & 3) + 8 * (rg >> 2) + 4 * hh;
    } else { lv[s] = 0u; li[s] = 0x7fffffff; }
  }
#pragma unroll 1
  for (int r = 0; r < NCAND; r++) {
    unsigned int bv = 0u;
    int bi = 0x7fffffff;
#pragma unroll
    for (int s = 0; s < 25; s++)
      if (lv[s] > bv || (lv[s] == bv && li[s] < bi)) { bv = lv[s]; bi = li[s]; }
#pragma unroll
    for (int m = 32; m; m >>= 1) {
      unsigned int ov = (unsigned int)__shfl_xor((int)bv, m, 64);
      int oi = __shfl_xor(bi, m, 64);
      if (ov > bv || (ov == bv && oi < bi)) { bv = ov; bi = oi; }
    }
    if (lane == r) fidx24[q * NCAND + r] = bi;
#pragma unroll
    for (int s = 0; s < 25; s++)
      if (li[s] == bi) lv[s] = 0u;
  }
}

// ---------- Kernel 6: fp64 exact rescore of 24 candidates -> final top-8 ----------
__global__ __launch_bounds__(256) void rescore_kernel(const double* __restrict__ q64n,
                                                      const float* __restrict__ keys,
                                                      const double* __restrict__ kinv64,
                                                      const int* __restrict__ fidx24,
                                                      float* __restrict__ scores_out,
                                                      int* __restrict__ fidx8,
                                                      float* __restrict__ usage_out) {
  const int q = blockIdx.x;
  const int tid = threadIdx.x;
  const int g = tid >> 3, l = tid & 7;
  __shared__ double sc[NCAND];
  __shared__ int    si[NCAND];
  __shared__ double s8[8];
  __shared__ int    f8[8];
  if (g < NCAND) {
    int idx = fidx24[q * NCAND + g];
    double s = 0.0;
    const double* qrow = &q64n[(long long)q * D + l * 32];
    const float* krow = &keys[(long long)idx * D + l * 32];
#pragma unroll
    for (int t = 0; t < 32; t++) s = fma(qrow[t], (double)krow[t], s);
#pragma unroll
    for (int m = 4; m; m >>= 1) s += __shfl_xor(s, m, 8);
    if (l == 0) { sc[g] = s * kinv64[idx]; si[g] = idx; }
  }
  __syncthreads();
  if (tid == 0) {
#pragma unroll 1
    for (int r = 0; r < 8; r++) {
      double bv = DNEG_INF;
      int bi = 0x7fffffff, bg = -1;
#pragma unroll
      for (int t = 0; t < NCAND; t++) {
        if (sc[t] > bv || (sc[t] == bv && si[t] < bi)) { bv = sc[t]; bi = si[t]; bg = t; }
      }
      s8[r] = bv; f8[r] = bi;
      sc[bg] = DNEG_INF;
    }
  }
  __syncthreads();
  if (tid < 8) {
    scores_out[q * 8 + tid] = (float)s8[tid];
    fidx8[q * 8 + tid] = f8[tid];
    atomicAdd(&usage_out[f8[tid]], 1.0f);
  }
}

// ---------- Kernel 7: gather retrieved values ----------
__global__ __launch_bounds__(256) void gather_kernel(const float* __restrict__ values,
                                                     const int* __restrict__ fidx8,
                                                     float* __restrict__ out_rv) {
  int wave = threadIdx.x >> 6, lane = threadIdx.x & 63;
  int row = blockIdx.x * 4 + wave;
  int idx = fidx8[row];
  float4 v = *(const float4*)(&values[(long long)idx * D + lane * 4]);
  *(float4*)(&out_rv[(long long)row * D + lane * 4]) = v;
}

extern "C" void kernel_launch(void* const* d_in, const int* in_sizes, int n_in,
                              void* d_out, int out_size, void* d_ws, size_t ws_size,
                              hipStream_t stream) {
  (void)in_sizes; (void)n_in; (void)out_size; (void)ws_size;
  const float* query  = (const float*)d_in[0];
  const float* W      = (const float*)d_in[1];
  const float* b      = (const float*)d_in[2];
  const float* keys   = (const float*)d_in[3];
  const float* values = (const float*)d_in[4];
  const float* usage  = (const float*)d_in[5];

  float* out    = (float*)d_out;
  float* out_rv = out;                    // 2048*8*256
  float* out_sc = out + BQ * 8 * D;       // 2048*8
  float* out_us = out_sc + BQ * 8;        // 50000

  double*         q64n   = (double*)d_ws;                     // 524288 d  (4MB)
  double*         kinv64 = q64n + BQ * D;                     // 50000 d
  unsigned short* qbf    = (unsigned short*)(kinv64 + NKEYS); // 524288 us (1MB)
  unsigned short* kbf    = qbf + BQ * D;                      // 50176*256 (25.7MB)
  unsigned int*   cand_p = (unsigned int*)(kbf + (long long)NKPAD * D); // 2048*1568 (12.9MB)
  int*            fidx24 = (int*)(cand_p + (long long)BQ * NC);         // 2048*24
  int*            fidx8  = fidx24 + BQ * NCAND;                         // 2048*8

  hipLaunchKernelGGL(qnorm_kernel, dim3(BQ / 32), dim3(256), 0, stream, query, W, b, qbf, q64n);
  hipLaunchKernelGGL(kprep_kernel, dim3(NKPAD / 4), dim3(256), 0, stream, keys, kinv64, kbf);
  hipLaunchKernelGGL(usage_copy_kernel, dim3((NKEYS + 255) / 256), dim3(256), 0, stream, usage, out_us);
  hipLaunchKernelGGL(sim_mfma_kernel, dim3(NCHUNK, BQ / 128), dim3(256), 0, stream, qbf, kbf, cand_p);
  hipLaunchKernelGGL(merge_kernel, dim3(BQ / 4), dim3(256), 0, stream, cand_p, fidx24);
  hipLaunchKernelGGL(rescore_kernel, dim3(BQ), dim3(256), 0, stream, q64n, keys, kinv64, fidx24, out_sc, fidx8, out_us);
  hipLaunchKernelGGL(gather_kernel, dim3(BQ * 8 / 4), dim3(256), 0, stream, values, fidx8, out_rv);
}

// Round 6
// 263.871 us; speedup vs baseline: 11.8808x; 1.5593x over previous
//
#include <hip/hip_runtime.h>

#define D 256
#define NKEYS 50000
#define KCHUNK 256
#define NCHUNK 196           // 50176 / 256
#define NKPAD (KCHUNK * NCHUNK)
#define BQ 2048
#define NC (NCHUNK * 8)      // 1568 candidates/query
#define NCAND 24             // rescored candidates per query
#define DNEG_INF (-1.0e300)

typedef __attribute__((ext_vector_type(8))) __bf16 bf16x8;
typedef __attribute__((ext_vector_type(16))) float f32x16;

// round-to-nearest-even f32 -> bf16 bits
__device__ __forceinline__ unsigned short f2bf(float x) {
  unsigned int u = __float_as_uint(x);
  unsigned int r = (u + 0x7fffu + ((u >> 16) & 1u)) >> 16;
  return (unsigned short)r;
}

// ---------- Kernel 1: q = query @ W^T + b (fp64 accum), L2-normalize ----------
__global__ __launch_bounds__(256) void qnorm_kernel(const float* __restrict__ query,
                                                    const float* __restrict__ W,
                                                    const float* __restrict__ b,
                                                    unsigned short* __restrict__ qbf,
                                                    double* __restrict__ q64n) {
  __shared__ __align__(16) float As[32][20];
  __shared__ __align__(16) float Bs[256][20];
  const int tid = threadIdx.x;
  const int qt = tid >> 5;
  const int nt = tid & 31;
  const int m0 = blockIdx.x * 32;

  double acc[4][8];
#pragma unroll
  for (int i = 0; i < 4; i++)
#pragma unroll
    for (int j = 0; j < 8; j++) acc[i][j] = 0.0;

  for (int k0 = 0; k0 < D; k0 += 16) {
    if (tid < 128) {
      int r = tid >> 2, f = tid & 3;
      *(float4*)(&As[r][f * 4]) = *(const float4*)(&query[(m0 + r) * D + k0 + f * 4]);
    }
#pragma unroll
    for (int i = 0; i < 4; i++) {
      int r = (tid >> 2) + 64 * i, f = tid & 3;
      *(float4*)(&Bs[r][f * 4]) = *(const float4*)(&W[r * D + k0 + f * 4]);
    }
    __syncthreads();
#pragma unroll
    for (int kk = 0; kk < 16; kk += 4) {
      float4 af[4];
#pragma unroll
      for (int i = 0; i < 4; i++) af[i] = *(const float4*)(&As[qt * 4 + i][kk]);
#pragma unroll
      for (int j = 0; j < 8; j++) {
        float4 bf = *(const float4*)(&Bs[nt + 32 * j][kk]);
#pragma unroll
        for (int i = 0; i < 4; i++) {
          acc[i][j] = fma((double)af[i].x, (double)bf.x, acc[i][j]);
          acc[i][j] = fma((double)af[i].y, (double)bf.y, acc[i][j]);
          acc[i][j] = fma((double)af[i].z, (double)bf.z, acc[i][j]);
          acc[i][j] = fma((double)af[i].w, (double)bf.w, acc[i][j]);
        }
      }
    }
    __syncthreads();
  }
#pragma unroll
  for (int i = 0; i < 4; i++)
#pragma unroll
    for (int j = 0; j < 8; j++) acc[i][j] += (double)b[nt + 32 * j];

#pragma unroll
  for (int i = 0; i < 4; i++) {
    double s = 0.0;
#pragma unroll
    for (int j = 0; j < 8; j++) s = fma(acc[i][j], acc[i][j], s);
#pragma unroll
    for (int m = 16; m; m >>= 1) s += __shfl_xor(s, m, 32);
    double den = fmax(sqrt(s), 1e-12);
    int row = m0 + qt * 4 + i;
#pragma unroll
    for (int j = 0; j < 8; j++) {
      double v = acc[i][j] / den;
      q64n[row * D + nt + 32 * j] = v;
      qbf[row * D + nt + 32 * j] = f2bf((float)v);
    }
  }
}

// ---------- Kernel 2: key prep: fp64 inv-norm + normalized bf16 keys, pre-swizzled ----------
// kbf row r (512B): 4 phase-blocks of 128B; within block elem e' = e ^ ((r&7)<<3).
__global__ __launch_bounds__(256) void kprep_kernel(const float* __restrict__ keys,
                                                    double* __restrict__ kinv64,
                                                    unsigned short* __restrict__ kbf) {
  int wave = threadIdx.x >> 6, lane = threadIdx.x & 63;
  int r = blockIdx.x * 4 + wave;
  if (r >= NKPAD) return;
  int c = lane * 4;
  int pb = c >> 6;
  int e = c & 63;
  int e2 = e ^ ((r & 7) << 3);
  unsigned short* dst = kbf + (long long)r * D + pb * 64 + e2;
  if (r >= NKEYS) {
    ushort4 z = {0, 0, 0, 0};
    *(ushort4*)dst = z;
    return;
  }
  float4 v = *(const float4*)(&keys[(long long)r * D + c]);
  double s = (double)v.x * v.x + (double)v.y * v.y + (double)v.z * v.z + (double)v.w * v.w;
#pragma unroll
  for (int m = 32; m; m >>= 1) s += __shfl_xor(s, m, 64);
  double inv = 1.0 / fmax(sqrt(s), 1e-12);
  if (lane == 0) kinv64[r] = inv;
  float fi = (float)inv;
  ushort4 o;
  o.x = f2bf(v.x * fi); o.y = f2bf(v.y * fi); o.z = f2bf(v.z * fi); o.w = f2bf(v.w * fi);
  *(ushort4*)dst = o;
}

// ---------- Kernel 3: usage copy ----------
__global__ void usage_copy_kernel(const float* __restrict__ usage, float* __restrict__ out_u) {
  int i = blockIdx.x * 256 + threadIdx.x;
  if (i < NKEYS) out_u[i] = usage[i];
}

// ---------- Kernel 4: 32x32x16 bf16 MFMA sim + packed-u32 top-8 ----------
// Block: 4 waves, 64 queries x 256 keys. Wave w: q-group qg=w>>1 (32 queries),
// key-half h=w&1 (128 keys). acc = 4 x f32x16 = 64 AGPR/wave.
// Per query: each wave finds half-chunk top-8 (sorted desc); halves merged via
// bitonic identity out[i]=max(A[i],B[7-i]) through LDS -> chunk top-8.
__global__ __launch_bounds__(256, 3) void sim_mfma_kernel(const unsigned short* __restrict__ qbf,
                                                          const unsigned short* __restrict__ kbf,
                                                          unsigned int* __restrict__ cand_p) {
  __shared__ __align__(16) unsigned char klds[KCHUNK * 128];  // 32KB
  __shared__ __align__(16) unsigned int mlds[2][32][2][8];    // 4KB pair-merge buffer
  const int tid = threadIdx.x;
  const int w = tid >> 6;
  const int l = tid & 63;
  const int col = l & 31;
  const int hi = l >> 5;
  const int qg = w >> 1;
  const int h = w & 1;
  const int n0 = blockIdx.x * KCHUNK;
  const int m0 = blockIdx.y * 64;
  const int qrow = m0 + qg * 32 + col;
  const int hbase = h * 128;

  f32x16 acc[4];
#pragma unroll
  for (int t = 0; t < 4; t++)
#pragma unroll
    for (int r = 0; r < 16; r++) acc[t][r] = 0.f;

  const int swz = (l & 7) << 4;
#pragma unroll
  for (int p = 0; p < 4; p++) {
    __syncthreads();
    // stage 32KB: 256 keys x 128B (phase p), linear LDS, swizzle pre-baked in kbf
#pragma unroll
    for (int i = 0; i < 8; i++) {
      int dstbase = (i * 4 + w) * 1024;
      int off = dstbase + l * 16;
      int r_loc = off >> 7;
      const void* src = (const char*)kbf + ((long long)(n0 + r_loc) * 512 + p * 128 + (off & 127));
      __builtin_amdgcn_global_load_lds(src, (void*)(klds + dstbase), 16, 0, 0);
    }
    // per-phase q fragments (transient 16 VGPR)
    bf16x8 qf[4];
#pragma unroll
    for (int s = 0; s < 4; s++)
      qf[s] = *(const bf16x8*)(qbf + (long long)qrow * D + (p * 4 + s) * 16 + hi * 8);
    __syncthreads();
#pragma unroll
    for (int t = 0; t < 4; t++) {
      int rowbase = (hbase + t * 32 + col) * 128 + hi * 16;
#pragma unroll
      for (int s = 0; s < 4; s++) {
        bf16x8 a = *(const bf16x8*)(klds + ((rowbase + s * 32) ^ swz));
        acc[t] = __builtin_amdgcn_mfma_f32_32x32x16_bf16(a, qf[s], acc[t], 0, 0, 0);
      }
    }
  }

  // pack scores -> monotone u32, chunk-local key in low 8 bits; invalid keys -> 0
  unsigned int pk[4][16];
  const bool edge = (n0 + KCHUNK > NKEYS);
#pragma unroll
  for (int t = 0; t < 4; t++)
#pragma unroll
    for (int r = 0; r < 16; r++) {
      unsigned int m = __float_as_uint(acc[t][r]);
      unsigned int u = (m & 0x80000000u) ? ~m : (m | 0x80000000u);
      int slot = hbase + t * 32 + (r & 3) + 8 * (r >> 2) + 4 * hi;
      unsigned int v = (u & 0xFFFFFF00u) | (unsigned)slot;
      if (edge && (n0 + slot >= NKEYS)) v = 0u;
      pk[t][r] = v;
    }

  // 8 rounds: umax over 64 regs, pair merge (xor 32), invalidate -> sorted desc win[8]
  unsigned int win[8];
#pragma unroll 1
  for (int r = 0; r < 8; r++) {
    unsigned int wv = 0u;
#pragma unroll
    for (int t = 0; t < 4; t++)
#pragma unroll
      for (int s = 0; s < 16; s++) wv = max(wv, pk[t][s]);
    unsigned int ov = (unsigned int)__shfl_xor((int)wv, 32, 64);
    unsigned int wm = max(wv, ov);
    win[r] = wm;
#pragma unroll
    for (int t = 0; t < 4; t++)
#pragma unroll
      for (int s = 0; s < 16; s++) pk[t][s] = (pk[t][s] == wm) ? 0u : pk[t][s];
  }

  // publish half-lists; even wave merges via bitonic pairwise max
  if (hi == 0) {
    uint4 a = {win[0], win[1], win[2], win[3]};
    uint4 b = {win[4], win[5], win[6], win[7]};
    *(uint4*)(&mlds[qg][col][h][0]) = a;
    *(uint4*)(&mlds[qg][col][h][4]) = b;
  }
  __syncthreads();
  if (h == 0 && hi == 0) {
    uint4 b0 = *(const uint4*)(&mlds[qg][col][1][0]);  // B[0..3]
    uint4 b1 = *(const uint4*)(&mlds[qg][col][1][4]);  // B[4..7]
    uint4 o0 = {max(win[0], b1.w), max(win[1], b1.z), max(win[2], b1.y), max(win[3], b1.x)};
    uint4 o1 = {max(win[4], b0.w), max(win[5], b0.z), max(win[6], b0.y), max(win[7], b0.x)};
    long long base = (long long)qrow * NC + blockIdx.x * 8;
    *(uint4*)(cand_p + base) = o0;
    *(uint4*)(cand_p + base + 4) = o1;
  }
}

// ---------- Kernel 5: merge 1568 candidates -> top-24 (one wave per query) ----------
__global__ __launch_bounds__(256) void merge_kernel(const unsigned int* __restrict__ cand_p,
                                                    int* __restrict__ fidx24) {
  const int q = blockIdx.x * 4 + (threadIdx.x >> 6);
  const int lane = threadIdx.x & 63;
  unsigned int lv[25];
  int li[25];
#pragma unroll
  for (int s = 0; s < 25; s++) {
    int c = lane + 64 * s;
    if (c < NC) {
      unsigned int p = cand_p[(long long)q * NC + c];
      lv[s] = p;
      li[s] = (c >> 3) * KCHUNK + (int)(p & 255u);
    } else { lv[s] = 0u; li[s] = 0x7fffffff; }
  }
#pragma unroll 1
  for (int r = 0; r < NCAND; r++) {
    unsigned int bv = 0u;
    int bi = 0x7fffffff;
#pragma unroll
    for (int s = 0; s < 25; s++)
      if (lv[s] > bv || (lv[s] == bv && li[s] < bi)) { bv = lv[s]; bi = li[s]; }
#pragma unroll
    for (int m = 32; m; m >>= 1) {
      unsigned int ov = (unsigned int)__shfl_xor((int)bv, m, 64);
      int oi = __shfl_xor(bi, m, 64);
      if (ov > bv || (ov == bv && oi < bi)) { bv = ov; bi = oi; }
    }
    if (lane == r) fidx24[q * NCAND + r] = bi;
#pragma unroll
    for (int s = 0; s < 25; s++)
      if (li[s] == bi) lv[s] = 0u;
  }
}

// ---------- Kernel 6: fp64 exact rescore of 24 candidates -> final top-8 ----------
__global__ __launch_bounds__(256) void rescore_kernel(const double* __restrict__ q64n,
                                                      const float* __restrict__ keys,
                                                      const double* __restrict__ kinv64,
                                                      const int* __restrict__ fidx24,
                                                      float* __restrict__ scores_out,
                                                      int* __restrict__ fidx8,
                                                      float* __restrict__ usage_out) {
  const int q = blockIdx.x;
  const int tid = threadIdx.x;
  const int g = tid >> 3, l = tid & 7;
  __shared__ double sc[NCAND];
  __shared__ int    si[NCAND];
  __shared__ double s8[8];
  __shared__ int    f8[8];
  if (g < NCAND) {
    int idx = fidx24[q * NCAND + g];
    double s = 0.0;
    const double* qrow = &q64n[(long long)q * D + l * 32];
    const float* krow = &keys[(long long)idx * D + l * 32];
#pragma unroll
    for (int t = 0; t < 32; t++) s = fma(qrow[t], (double)krow[t], s);
#pragma unroll
    for (int m = 4; m; m >>= 1) s += __shfl_xor(s, m, 8);
    if (l == 0) { sc[g] = s * kinv64[idx]; si[g] = idx; }
  }
  __syncthreads();
  if (tid == 0) {
#pragma unroll 1
    for (int r = 0; r < 8; r++) {
      double bv = DNEG_INF;
      int bi = 0x7fffffff, bg = -1;
#pragma unroll
      for (int t = 0; t < NCAND; t++) {
        if (sc[t] > bv || (sc[t] == bv && si[t] < bi)) { bv = sc[t]; bi = si[t]; bg = t; }
      }
      s8[r] = bv; f8[r] = bi;
      sc[bg] = DNEG_INF;
    }
  }
  __syncthreads();
  if (tid < 8) {
    scores_out[q * 8 + tid] = (float)s8[tid];
    fidx8[q * 8 + tid] = f8[tid];
    atomicAdd(&usage_out[f8[tid]], 1.0f);
  }
}

// ---------- Kernel 7: gather retrieved values ----------
__global__ __launch_bounds__(256) void gather_kernel(const float* __restrict__ values,
                                                     const int* __restrict__ fidx8,
                                                     float* __restrict__ out_rv) {
  int wave = threadIdx.x >> 6, lane = threadIdx.x & 63;
  int row = blockIdx.x * 4 + wave;
  int idx = fidx8[row];
  float4 v = *(const float4*)(&values[(long long)idx * D + lane * 4]);
  *(float4*)(&out_rv[(long long)row * D + lane * 4]) = v;
}

extern "C" void kernel_launch(void* const* d_in, const int* in_sizes, int n_in,
                              void* d_out, int out_size, void* d_ws, size_t ws_size,
                              hipStream_t stream) {
  (void)in_sizes; (void)n_in; (void)out_size; (void)ws_size;
  const float* query  = (const float*)d_in[0];
  const float* W      = (const float*)d_in[1];
  const float* b      = (const float*)d_in[2];
  const float* keys   = (const float*)d_in[3];
  const float* values = (const float*)d_in[4];
  const float* usage  = (const float*)d_in[5];

  float* out    = (float*)d_out;
  float* out_rv = out;                    // 2048*8*256
  float* out_sc = out + BQ * 8 * D;       // 2048*8
  float* out_us = out_sc + BQ * 8;        // 50000

  double*         q64n   = (double*)d_ws;                     // 524288 d  (4MB)
  double*         kinv64 = q64n + BQ * D;                     // 50000 d
  unsigned short* qbf    = (unsigned short*)(kinv64 + NKEYS); // 524288 us (1MB)
  unsigned short* kbf    = qbf + BQ * D;                      // 50176*256 (25.7MB)
  unsigned int*   cand_p = (unsigned int*)(kbf + (long long)NKPAD * D); // 2048*1568 (12.9MB)
  int*            fidx24 = (int*)(cand_p + (long long)BQ * NC);         // 2048*24
  int*            fidx8  = fidx24 + BQ * NCAND;                         // 2048*8

  hipLaunchKernelGGL(qnorm_kernel, dim3(BQ / 32), dim3(256), 0, stream, query, W, b, qbf, q64n);
  hipLaunchKernelGGL(kprep_kernel, dim3(NKPAD / 4), dim3(256), 0, stream, keys, kinv64, kbf);
  hipLaunchKernelGGL(usage_copy_kernel, dim3((NKEYS + 255) / 256), dim3(256), 0, stream, usage, out_us);
  hipLaunchKernelGGL(sim_mfma_kernel, dim3(NCHUNK, BQ / 64), dim3(256), 0, stream, qbf, kbf, cand_p);
  hipLaunchKernelGGL(merge_kernel, dim3(BQ / 4), dim3(256), 0, stream, cand_p, fidx24);
  hipLaunchKernelGGL(rescore_kernel, dim3(BQ), dim3(256), 0, stream, q64n, keys, kinv64, fidx24, out_sc, fidx8, out_us);
  hipLaunchKernelGGL(gather_kernel, dim3(BQ * 8 / 4), dim3(256), 0, stream, values, fidx8, out_rv);
}

// Round 7
// 236.350 us; speedup vs baseline: 13.2642x; 1.1164x over previous
//
#include <hip/hip_runtime.h>

#define D 256
#define NKEYS 50000
#define KCHUNK 256
#define NCHUNK 196           // 50176 / 256
#define NKPAD (KCHUNK * NCHUNK)
#define BQ 2048
#define NC (NCHUNK * 4)      // 784 candidates/query
#define NCAND 24             // rescored candidates per query
#define DNEG_INF (-1.0e300)

typedef __attribute__((ext_vector_type(8))) __bf16 bf16x8;
typedef __attribute__((ext_vector_type(16))) float f32x16;

// round-to-nearest-even f32 -> bf16 bits
__device__ __forceinline__ unsigned short f2bf(float x) {
  unsigned int u = __float_as_uint(x);
  unsigned int r = (u + 0x7fffu + ((u >> 16) & 1u)) >> 16;
  return (unsigned short)r;
}

// ---------- Kernel 1: q = query @ W^T + b (fp64 accum), L2-normalize ----------
// 128 blocks x 16 query rows.
__global__ __launch_bounds__(256) void qnorm_kernel(const float* __restrict__ query,
                                                    const float* __restrict__ W,
                                                    const float* __restrict__ b,
                                                    unsigned short* __restrict__ qbf,
                                                    double* __restrict__ q64n) {
  __shared__ __align__(16) float As[16][20];
  __shared__ __align__(16) float Bs[256][20];
  const int tid = threadIdx.x;
  const int qt = tid >> 5;   // 8 groups -> rows qt*2+i
  const int nt = tid & 31;   // cols nt + 32*j, j<8
  const int m0 = blockIdx.x * 16;

  double acc[2][8];
#pragma unroll
  for (int i = 0; i < 2; i++)
#pragma unroll
    for (int j = 0; j < 8; j++) acc[i][j] = 0.0;

  for (int k0 = 0; k0 < D; k0 += 16) {
    if (tid < 64) {
      int r = tid >> 2, f = tid & 3;
      *(float4*)(&As[r][f * 4]) = *(const float4*)(&query[(m0 + r) * D + k0 + f * 4]);
    }
#pragma unroll
    for (int i = 0; i < 4; i++) {
      int r = (tid >> 2) + 64 * i, f = tid & 3;
      *(float4*)(&Bs[r][f * 4]) = *(const float4*)(&W[r * D + k0 + f * 4]);
    }
    __syncthreads();
#pragma unroll
    for (int kk = 0; kk < 16; kk += 4) {
      float4 af[2];
#pragma unroll
      for (int i = 0; i < 2; i++) af[i] = *(const float4*)(&As[qt * 2 + i][kk]);
#pragma unroll
      for (int j = 0; j < 8; j++) {
        float4 bf = *(const float4*)(&Bs[nt + 32 * j][kk]);
#pragma unroll
        for (int i = 0; i < 2; i++) {
          acc[i][j] = fma((double)af[i].x, (double)bf.x, acc[i][j]);
          acc[i][j] = fma((double)af[i].y, (double)bf.y, acc[i][j]);
          acc[i][j] = fma((double)af[i].z, (double)bf.z, acc[i][j]);
          acc[i][j] = fma((double)af[i].w, (double)bf.w, acc[i][j]);
        }
      }
    }
    __syncthreads();
  }
#pragma unroll
  for (int i = 0; i < 2; i++)
#pragma unroll
    for (int j = 0; j < 8; j++) acc[i][j] += (double)b[nt + 32 * j];

#pragma unroll
  for (int i = 0; i < 2; i++) {
    double s = 0.0;
#pragma unroll
    for (int j = 0; j < 8; j++) s = fma(acc[i][j], acc[i][j], s);
#pragma unroll
    for (int m = 16; m; m >>= 1) s += __shfl_xor(s, m, 32);
    double den = fmax(sqrt(s), 1e-12);
    int row = m0 + qt * 2 + i;
#pragma unroll
    for (int j = 0; j < 8; j++) {
      double v = acc[i][j] / den;
      q64n[row * D + nt + 32 * j] = v;
      qbf[row * D + nt + 32 * j] = f2bf((float)v);
    }
  }
}

// ---------- Kernel 2: key prep: fp64 inv-norm + normalized bf16 keys, pre-swizzled ----------
// kbf row r (512B): 4 phase-blocks of 128B; within block elem e' = e ^ ((r&7)<<3).
__global__ __launch_bounds__(256) void kprep_kernel(const float* __restrict__ keys,
                                                    double* __restrict__ kinv64,
                                                    unsigned short* __restrict__ kbf) {
  int wave = threadIdx.x >> 6, lane = threadIdx.x & 63;
  int r = blockIdx.x * 4 + wave;
  if (r >= NKPAD) return;
  int c = lane * 4;
  int pb = c >> 6;
  int e = c & 63;
  int e2 = e ^ ((r & 7) << 3);
  unsigned short* dst = kbf + (long long)r * D + pb * 64 + e2;
  if (r >= NKEYS) {
    ushort4 z = {0, 0, 0, 0};
    *(ushort4*)dst = z;
    return;
  }
  float4 v = *(const float4*)(&keys[(long long)r * D + c]);
  double s = (double)v.x * v.x + (double)v.y * v.y + (double)v.z * v.z + (double)v.w * v.w;
#pragma unroll
  for (int m = 32; m; m >>= 1) s += __shfl_xor(s, m, 64);
  double inv = 1.0 / fmax(sqrt(s), 1e-12);
  if (lane == 0) kinv64[r] = inv;
  float fi = (float)inv;
  ushort4 o;
  o.x = f2bf(v.x * fi); o.y = f2bf(v.y * fi); o.z = f2bf(v.z * fi); o.w = f2bf(v.w * fi);
  *(ushort4*)dst = o;
}

// ---------- Kernel 3: usage copy ----------
__global__ void usage_copy_kernel(const float* __restrict__ usage, float* __restrict__ out_u) {
  int i = blockIdx.x * 256 + threadIdx.x;
  if (i < NKEYS) out_u[i] = usage[i];
}

// ---------- Kernel 4: 32x32x16 bf16 MFMA sim + packed-u32 top-4 per chunk ----------
// Block: 4 waves, 64 queries x 256 keys. Wave w: q-group qg=w>>1, key-half h=w&1.
__global__ __launch_bounds__(256, 3) void sim_mfma_kernel(const unsigned short* __restrict__ qbf,
                                                          const unsigned short* __restrict__ kbf,
                                                          unsigned int* __restrict__ cand_p) {
  __shared__ __align__(16) unsigned char klds[KCHUNK * 128];  // 32KB
  __shared__ __align__(16) unsigned int mlds[2][32][2][4];    // 2KB pair-merge buffer
  const int tid = threadIdx.x;
  const int w = tid >> 6;
  const int l = tid & 63;
  const int col = l & 31;
  const int hi = l >> 5;
  const int qg = w >> 1;
  const int h = w & 1;
  const int n0 = blockIdx.x * KCHUNK;
  const int m0 = blockIdx.y * 64;
  const int qrow = m0 + qg * 32 + col;
  const int hbase = h * 128;

  f32x16 acc[4];
#pragma unroll
  for (int t = 0; t < 4; t++)
#pragma unroll
    for (int r = 0; r < 16; r++) acc[t][r] = 0.f;

  const int swz = (l & 7) << 4;
#pragma unroll
  for (int p = 0; p < 4; p++) {
    __syncthreads();
#pragma unroll
    for (int i = 0; i < 8; i++) {
      int dstbase = (i * 4 + w) * 1024;
      int off = dstbase + l * 16;
      int r_loc = off >> 7;
      const void* src = (const char*)kbf + ((long long)(n0 + r_loc) * 512 + p * 128 + (off & 127));
      __builtin_amdgcn_global_load_lds(src, (void*)(klds + dstbase), 16, 0, 0);
    }
    bf16x8 qf[4];
#pragma unroll
    for (int s = 0; s < 4; s++)
      qf[s] = *(const bf16x8*)(qbf + (long long)qrow * D + (p * 4 + s) * 16 + hi * 8);
    __syncthreads();
#pragma unroll
    for (int t = 0; t < 4; t++) {
      int rowbase = (hbase + t * 32 + col) * 128 + hi * 16;
#pragma unroll
      for (int s = 0; s < 4; s++) {
        bf16x8 a = *(const bf16x8*)(klds + ((rowbase + s * 32) ^ swz));
        acc[t] = __builtin_amdgcn_mfma_f32_32x32x16_bf16(a, qf[s], acc[t], 0, 0, 0);
      }
    }
  }

  // pack scores -> monotone u32, chunk-local key slot in low 8 bits; invalid -> 0
  unsigned int pk[4][16];
  const bool edge = (n0 + KCHUNK > NKEYS);
#pragma unroll
  for (int t = 0; t < 4; t++)
#pragma unroll
    for (int r = 0; r < 16; r++) {
      unsigned int m = __float_as_uint(acc[t][r]);
      unsigned int u = m ^ ((unsigned int)((int)m >> 31) | 0x80000000u);
      int slot = hbase + t * 32 + (r & 3) + 8 * (r >> 2) + 4 * hi;
      unsigned int v = (u & 0xFFFFFF00u) | (unsigned)slot;
      if (edge && (n0 + slot >= NKEYS)) v = 0u;
      pk[t][r] = v;
    }

  // 4 rounds: umax over 64 regs (max3-fusable chain), pair merge (xor 32), invalidate
  unsigned int win[4];
#pragma unroll 1
  for (int r = 0; r < 4; r++) {
    unsigned int wv = 0u;
#pragma unroll
    for (int t = 0; t < 4; t++)
#pragma unroll
      for (int s = 0; s < 16; s++) wv = max(wv, pk[t][s]);
    unsigned int ov = (unsigned int)__shfl_xor((int)wv, 32, 64);
    unsigned int wm = max(wv, ov);
    win[r] = wm;
#pragma unroll
    for (int t = 0; t < 4; t++)
#pragma unroll
      for (int s = 0; s < 16; s++) pk[t][s] = (pk[t][s] == wm) ? 0u : pk[t][s];
  }

  // publish half-lists (sorted desc); even wave merges via bitonic pairwise max
  if (hi == 0) {
    uint4 a = {win[0], win[1], win[2], win[3]};
    *(uint4*)(&mlds[qg][col][h][0]) = a;
  }
  __syncthreads();
  if (h == 0 && hi == 0) {
    uint4 bb = *(const uint4*)(&mlds[qg][col][1][0]);
    uint4 o0 = {max(win[0], bb.w), max(win[1], bb.z), max(win[2], bb.y), max(win[3], bb.x)};
    long long base = (long long)qrow * NC + blockIdx.x * 4;
    *(uint4*)(cand_p + base) = o0;
  }
}

// ---------- Kernel 5: finalize: merge 784 -> top-24, fp64 rescore, top-8, usage, gather ----------
__global__ __launch_bounds__(256) void finalize_kernel(const unsigned int* __restrict__ cand_p,
                                                       const double* __restrict__ q64n,
                                                       const float* __restrict__ keys,
                                                       const double* __restrict__ kinv64,
                                                       const float* __restrict__ values,
                                                       float* __restrict__ scores_out,
                                                       float* __restrict__ out_rv,
                                                       float* __restrict__ usage_out) {
  const int q = blockIdx.x;
  const int tid = threadIdx.x;
  __shared__ int    cidx[NCAND];
  __shared__ double sc[NCAND];
  __shared__ double s8[8];
  __shared__ int    f8[8];

  // Phase A: wave 0 extracts bf16-top-24 of the 784 candidates
  if (tid < 64) {
    const int lane = tid;
    unsigned int lv[13];
    int li[13];
#pragma unroll
    for (int s = 0; s < 13; s++) {
      int c = lane + 64 * s;
      if (c < NC) {
        unsigned int p = cand_p[(long long)q * NC + c];
        lv[s] = p;
        li[s] = (c >> 2) * KCHUNK + (int)(p & 255u);
      } else { lv[s] = 0u; li[s] = 0x7fffffff; }
    }
#pragma unroll 1
    for (int r = 0; r < NCAND; r++) {
      unsigned int bv = 0u;
      int bi = 0x7fffffff;
#pragma unroll
      for (int s = 0; s < 13; s++)
        if (lv[s] > bv || (lv[s] == bv && li[s] < bi)) { bv = lv[s]; bi = li[s]; }
#pragma unroll
      for (int m = 32; m; m >>= 1) {
        unsigned int ov = (unsigned int)__shfl_xor((int)bv, m, 64);
        int oi = __shfl_xor(bi, m, 64);
        if (ov > bv || (ov == bv && oi < bi)) { bv = ov; bi = oi; }
      }
      if (lane == r) cidx[r] = bi;
#pragma unroll
      for (int s = 0; s < 13; s++)
        if (li[s] == bi) lv[s] = 0u;
    }
  }
  __syncthreads();

  // Phase B: fp64 rescore of 24 candidates (8 lanes each)
  {
    const int g = tid >> 3, l = tid & 7;
    if (g < NCAND) {
      int idx = cidx[g];
      double s = 0.0;
      const double* qrow = &q64n[(long long)q * D + l * 32];
      const float* krow = &keys[(long long)idx * D + l * 32];
#pragma unroll
      for (int t = 0; t < 32; t++) s = fma(qrow[t], (double)krow[t], s);
#pragma unroll
      for (int m = 4; m; m >>= 1) s += __shfl_xor(s, m, 8);
      if (l == 0) sc[g] = s * kinv64[idx];
    }
  }
  __syncthreads();

  // Phase C: serial exact top-8
  if (tid == 0) {
#pragma unroll 1
    for (int r = 0; r < 8; r++) {
      double bv = DNEG_INF;
      int bi = 0x7fffffff, bg = -1;
#pragma unroll
      for (int t = 0; t < NCAND; t++) {
        if (sc[t] > bv || (sc[t] == bv && cidx[t] < bi)) { bv = sc[t]; bi = cidx[t]; bg = t; }
      }
      s8[r] = bv; f8[r] = bi;
      sc[bg] = DNEG_INF;
    }
  }
  __syncthreads();
  if (tid < 8) {
    scores_out[q * 8 + tid] = (float)s8[tid];
    atomicAdd(&usage_out[f8[tid]], 1.0f);
  }

  // Phase D: gather 8 x 256 values
  {
    const int row = tid >> 5;         // 0..7
    const int c0 = (tid & 31) * 8;    // 8 floats per thread
    int idx = f8[row];
    float4 v0 = *(const float4*)(&values[(long long)idx * D + c0]);
    float4 v1 = *(const float4*)(&values[(long long)idx * D + c0 + 4]);
    long long obase = ((long long)q * 8 + row) * D + c0;
    *(float4*)(&out_rv[obase]) = v0;
    *(float4*)(&out_rv[obase + 4]) = v1;
  }
}

extern "C" void kernel_launch(void* const* d_in, const int* in_sizes, int n_in,
                              void* d_out, int out_size, void* d_ws, size_t ws_size,
                              hipStream_t stream) {
  (void)in_sizes; (void)n_in; (void)out_size; (void)ws_size;
  const float* query  = (const float*)d_in[0];
  const float* W      = (const float*)d_in[1];
  const float* b      = (const float*)d_in[2];
  const float* keys   = (const float*)d_in[3];
  const float* values = (const float*)d_in[4];
  const float* usage  = (const float*)d_in[5];

  float* out    = (float*)d_out;
  float* out_rv = out;                    // 2048*8*256
  float* out_sc = out + BQ * 8 * D;       // 2048*8
  float* out_us = out_sc + BQ * 8;        // 50000

  double*         q64n   = (double*)d_ws;                     // 524288 d  (4MB)
  double*         kinv64 = q64n + BQ * D;                     // 50000 d
  unsigned short* qbf    = (unsigned short*)(kinv64 + NKEYS); // 524288 us (1MB)
  unsigned short* kbf    = qbf + BQ * D;                      // 50176*256 (25.7MB)
  unsigned int*   cand_p = (unsigned int*)(kbf + (long long)NKPAD * D); // 2048*784 (6.4MB)

  hipLaunchKernelGGL(qnorm_kernel, dim3(BQ / 16), dim3(256), 0, stream, query, W, b, qbf, q64n);
  hipLaunchKernelGGL(kprep_kernel, dim3(NKPAD / 4), dim3(256), 0, stream, keys, kinv64, kbf);
  hipLaunchKernelGGL(usage_copy_kernel, dim3((NKEYS + 255) / 256), dim3(256), 0, stream, usage, out_us);
  hipLaunchKernelGGL(sim_mfma_kernel, dim3(NCHUNK, BQ / 64), dim3(256), 0, stream, qbf, kbf, cand_p);
  hipLaunchKernelGGL(finalize_kernel, dim3(BQ), dim3(256), 0, stream, cand_p, q64n, keys, kinv64, values, out_sc, out_rv, out_us);
}

// Round 8
// 210.747 us; speedup vs baseline: 14.8756x; 1.1215x over previous
//
#include <hip/hip_runtime.h>

#define D 256
#define NKEYS 50000
#define KCHUNK 256
#define NCHUNK 196           // ceil(50000/256) padded
#define NKPAD (KCHUNK * NCHUNK)
#define BQ 2048
#define NC (NCHUNK * 4)      // 784 candidates/query
#define NCAND 24             // rescored candidates per query
#define DNEG_INF (-1.0e300)

typedef __attribute__((ext_vector_type(8))) __bf16 bf16x8;
typedef __attribute__((ext_vector_type(16))) float f32x16;

// round-to-nearest-even f32 -> bf16 bits
__device__ __forceinline__ unsigned short f2bf(float x) {
  unsigned int u = __float_as_uint(x);
  unsigned int r = (u + 0x7fffu + ((u >> 16) & 1u)) >> 16;
  return (unsigned short)r;
}

// ---------- Kernel 1: q = query @ W^T + b (fp64 accum), L2-normalize ----------
__global__ __launch_bounds__(256) void qnorm_kernel(const float* __restrict__ query,
                                                    const float* __restrict__ W,
                                                    const float* __restrict__ b,
                                                    unsigned short* __restrict__ qbf,
                                                    double* __restrict__ q64n) {
  __shared__ __align__(16) float As[16][20];
  __shared__ __align__(16) float Bs[256][20];
  const int tid = threadIdx.x;
  const int qt = tid >> 5;
  const int nt = tid & 31;
  const int m0 = blockIdx.x * 16;

  double acc[2][8];
#pragma unroll
  for (int i = 0; i < 2; i++)
#pragma unroll
    for (int j = 0; j < 8; j++) acc[i][j] = 0.0;

  for (int k0 = 0; k0 < D; k0 += 16) {
    if (tid < 64) {
      int r = tid >> 2, f = tid & 3;
      *(float4*)(&As[r][f * 4]) = *(const float4*)(&query[(m0 + r) * D + k0 + f * 4]);
    }
#pragma unroll
    for (int i = 0; i < 4; i++) {
      int r = (tid >> 2) + 64 * i, f = tid & 3;
      *(float4*)(&Bs[r][f * 4]) = *(const float4*)(&W[r * D + k0 + f * 4]);
    }
    __syncthreads();
#pragma unroll
    for (int kk = 0; kk < 16; kk += 4) {
      float4 af[2];
#pragma unroll
      for (int i = 0; i < 2; i++) af[i] = *(const float4*)(&As[qt * 2 + i][kk]);
#pragma unroll
      for (int j = 0; j < 8; j++) {
        float4 bf = *(const float4*)(&Bs[nt + 32 * j][kk]);
#pragma unroll
        for (int i = 0; i < 2; i++) {
          acc[i][j] = fma((double)af[i].x, (double)bf.x, acc[i][j]);
          acc[i][j] = fma((double)af[i].y, (double)bf.y, acc[i][j]);
          acc[i][j] = fma((double)af[i].z, (double)bf.z, acc[i][j]);
          acc[i][j] = fma((double)af[i].w, (double)bf.w, acc[i][j]);
        }
      }
    }
    __syncthreads();
  }
#pragma unroll
  for (int i = 0; i < 2; i++)
#pragma unroll
    for (int j = 0; j < 8; j++) acc[i][j] += (double)b[nt + 32 * j];

#pragma unroll
  for (int i = 0; i < 2; i++) {
    double s = 0.0;
#pragma unroll
    for (int j = 0; j < 8; j++) s = fma(acc[i][j], acc[i][j], s);
#pragma unroll
    for (int m = 16; m; m >>= 1) s += __shfl_xor(s, m, 32);
    double den = fmax(sqrt(s), 1e-12);
    int row = m0 + qt * 2 + i;
#pragma unroll
    for (int j = 0; j < 8; j++) {
      double v = acc[i][j] / den;
      q64n[row * D + nt + 32 * j] = v;
      qbf[row * D + nt + 32 * j] = f2bf((float)v);
    }
  }
}

// ---------- Kernel 2: key prep (+ fused usage copy) ----------
// kbf row r (512B): 4 phase-blocks of 128B; within block elem e' = e ^ ((r&7)<<3).
__global__ __launch_bounds__(256) void kprep_kernel(const float* __restrict__ keys,
                                                    const float* __restrict__ usage,
                                                    double* __restrict__ kinv64,
                                                    unsigned short* __restrict__ kbf,
                                                    float* __restrict__ out_u) {
  int wave = threadIdx.x >> 6, lane = threadIdx.x & 63;
  int r = blockIdx.x * 4 + wave;
  if (r >= NKPAD) return;
  if (lane == 0 && r < NKEYS) out_u[r] = usage[r];
  int c = lane * 4;
  int pb = c >> 6;
  int e = c & 63;
  int e2 = e ^ ((r & 7) << 3);
  unsigned short* dst = kbf + (long long)r * D + pb * 64 + e2;
  if (r >= NKEYS) {
    ushort4 z = {0, 0, 0, 0};
    *(ushort4*)dst = z;
    return;
  }
  float4 v = *(const float4*)(&keys[(long long)r * D + c]);
  double s = (double)v.x * v.x + (double)v.y * v.y + (double)v.z * v.z + (double)v.w * v.w;
#pragma unroll
  for (int m = 32; m; m >>= 1) s += __shfl_xor(s, m, 64);
  double inv = 1.0 / fmax(sqrt(s), 1e-12);
  if (lane == 0) kinv64[r] = inv;
  float fi = (float)inv;
  ushort4 o;
  o.x = f2bf(v.x * fi); o.y = f2bf(v.y * fi); o.z = f2bf(v.z * fi); o.w = f2bf(v.w * fi);
  *(ushort4*)dst = o;
}

// ---------- Kernel 3: 32x32x16 bf16 MFMA sim + streaming-insert top-4 per chunk ----------
// 1D grid 6400: k8=bid&7 (XCD), i=bid>>3, qt=i&31, chunk=(i>>5)*8+k8 -> each XCD
// sweeps all q-tiles of its own chunk subset (chunk L2-resident per XCD).
// Block: 4 waves, 64 queries x 256 keys. Wave w: q-group qg=w>>1, key-half h=w&1.
__global__ __launch_bounds__(256, 4) void sim_mfma_kernel(const unsigned short* __restrict__ qbf,
                                                          const unsigned short* __restrict__ kbf,
                                                          unsigned int* __restrict__ cand_p) {
  __shared__ __align__(16) unsigned char klds[KCHUNK * 128];  // 32KB
  __shared__ __align__(16) unsigned int mlds[2][32][2][4];    // 2KB pair-merge buffer
  const int bid = blockIdx.x;
  const int k8 = bid & 7;
  const int ii = bid >> 3;
  const int qt = ii & 31;
  const int chunk = (ii >> 5) * 8 + k8;
  if (chunk >= NCHUNK) return;
  const int n0 = chunk * KCHUNK;
  const int m0 = qt * 64;

  const int tid = threadIdx.x;
  const int w = tid >> 6;
  const int l = tid & 63;
  const int col = l & 31;
  const int hi = l >> 5;
  const int qg = w >> 1;
  const int h = w & 1;
  const int qrow = m0 + qg * 32 + col;
  const int hbase = h * 128;

  f32x16 acc[4];
#pragma unroll
  for (int t = 0; t < 4; t++)
#pragma unroll
    for (int r = 0; r < 16; r++) acc[t][r] = 0.f;

  const int swz = (l & 7) << 4;
#pragma unroll
  for (int p = 0; p < 4; p++) {
    __syncthreads();
#pragma unroll
    for (int i = 0; i < 8; i++) {
      int dstbase = (i * 4 + w) * 1024;
      int off = dstbase + l * 16;
      int r_loc = off >> 7;
      const void* src = (const char*)kbf + ((long long)(n0 + r_loc) * 512 + p * 128 + (off & 127));
      __builtin_amdgcn_global_load_lds(src, (void*)(klds + dstbase), 16, 0, 0);
    }
    bf16x8 qf[4];
#pragma unroll
    for (int s = 0; s < 4; s++)
      qf[s] = *(const bf16x8*)(qbf + (long long)qrow * D + (p * 4 + s) * 16 + hi * 8);
    __syncthreads();
#pragma unroll
    for (int t = 0; t < 4; t++) {
      int rowbase = (hbase + t * 32 + col) * 128 + hi * 16;
#pragma unroll
      for (int s = 0; s < 4; s++) {
        bf16x8 a = *(const bf16x8*)(klds + ((rowbase + s * 32) ^ swz));
        acc[t] = __builtin_amdgcn_mfma_f32_32x32x16_bf16(a, qf[s], acc[t], 0, 0, 0);
      }
    }
  }

  // streaming pack + insertion top-4 (sorted desc s0>=s1>=s2>=s3).
  // pack: score in [-1,1] -> score+2.0 in [1,3) -> as_uint monotone; slot in low 8 bits.
  unsigned int s0 = 0u, s1 = 0u, s2 = 0u, s3 = 0u;
  const bool edge = (n0 + KCHUNK > NKEYS);
#pragma unroll
  for (int t = 0; t < 4; t++)
#pragma unroll
    for (int r = 0; r < 16; r++) {
      unsigned int u = __float_as_uint(acc[t][r] + 2.0f);
      int slot = hbase + t * 32 + (r & 3) + 8 * (r >> 2) + 4 * hi;
      unsigned int v = (u & 0xFFFFFF00u) | (unsigned)slot;
      if (edge && (n0 + slot >= NKEYS)) v = 0u;
      unsigned int m0v = min(s0, v); s0 = max(s0, v);
      unsigned int m1v = min(s1, m0v); s1 = max(s1, m0v);
      unsigned int m2v = min(s2, m1v); s2 = max(s2, m1v);
      s3 = max(s3, m2v);
    }

  // lane-pair merge (l ^ 32 shares the query col): bitonic top-4 + sort-4
  unsigned int b0 = (unsigned int)__shfl_xor((int)s0, 32, 64);
  unsigned int b1 = (unsigned int)__shfl_xor((int)s1, 32, 64);
  unsigned int b2 = (unsigned int)__shfl_xor((int)s2, 32, 64);
  unsigned int b3 = (unsigned int)__shfl_xor((int)s3, 32, 64);
  unsigned int t0 = max(s0, b3), t1 = max(s1, b2), t2 = max(s2, b1), t3 = max(s3, b0);
  unsigned int u0 = max(t0, t2), u2 = min(t0, t2), u1 = max(t1, t3), u3 = min(t1, t3);
  unsigned int w0 = max(u0, u1), w1 = min(u0, u1), w2 = max(u2, u3), w3 = min(u2, u3);

  // cross-wave (key-half) merge via LDS; sorted inputs -> pairwise max
  if (hi == 0) {
    uint4 a = {w0, w1, w2, w3};
    *(uint4*)(&mlds[qg][col][h][0]) = a;
  }
  __syncthreads();
  if (h == 0 && hi == 0) {
    uint4 bb = *(const uint4*)(&mlds[qg][col][1][0]);
    uint4 o = {max(w0, bb.w), max(w1, bb.z), max(w2, bb.y), max(w3, bb.x)};
    long long base = (long long)qrow * NC + chunk * 4;
    *(uint4*)(cand_p + base) = o;
  }
}

// ---------- Kernel 4: finalize: merge 784 -> top-24, fp64 rescore, top-8, usage, gather ----------
__global__ __launch_bounds__(256) void finalize_kernel(const unsigned int* __restrict__ cand_p,
                                                       const double* __restrict__ q64n,
                                                       const float* __restrict__ keys,
                                                       const double* __restrict__ kinv64,
                                                       const float* __restrict__ values,
                                                       float* __restrict__ scores_out,
                                                       float* __restrict__ out_rv,
                                                       float* __restrict__ usage_out) {
  const int q = blockIdx.x;
  const int tid = threadIdx.x;
  __shared__ int    cidx[NCAND];
  __shared__ double sc[NCAND];
  __shared__ double s8[8];
  __shared__ int    f8[8];

  // Phase A: wave 0 extracts bf16-top-24 of the 784 candidates
  if (tid < 64) {
    const int lane = tid;
    unsigned int lv[13];
    int li[13];
#pragma unroll
    for (int s = 0; s < 13; s++) {
      int c = lane + 64 * s;
      if (c < NC) {
        unsigned int p = cand_p[(long long)q * NC + c];
        lv[s] = p;
        li[s] = (c >> 2) * KCHUNK + (int)(p & 255u);
      } else { lv[s] = 0u; li[s] = 0x7fffffff; }
    }
#pragma unroll 1
    for (int r = 0; r < NCAND; r++) {
      unsigned int bv = 0u;
      int bi = 0x7fffffff;
#pragma unroll
      for (int s = 0; s < 13; s++)
        if (lv[s] > bv || (lv[s] == bv && li[s] < bi)) { bv = lv[s]; bi = li[s]; }
#pragma unroll
      for (int m = 32; m; m >>= 1) {
        unsigned int ov = (unsigned int)__shfl_xor((int)bv, m, 64);
        int oi = __shfl_xor(bi, m, 64);
        if (ov > bv || (ov == bv && oi < bi)) { bv = ov; bi = oi; }
      }
      if (lane == r) cidx[r] = bi;
#pragma unroll
      for (int s = 0; s < 13; s++)
        if (li[s] == bi) lv[s] = 0u;
    }
  }
  __syncthreads();

  // Phase B: fp64 rescore of 24 candidates (8 lanes each)
  {
    const int g = tid >> 3, l = tid & 7;
    if (g < NCAND) {
      int idx = cidx[g];
      double s = 0.0;
      const double* qrow = &q64n[(long long)q * D + l * 32];
      const float* krow = &keys[(long long)idx * D + l * 32];
#pragma unroll
      for (int t = 0; t < 32; t++) s = fma(qrow[t], (double)krow[t], s);
#pragma unroll
      for (int m = 4; m; m >>= 1) s += __shfl_xor(s, m, 8);
      if (l == 0) sc[g] = s * kinv64[idx];
    }
  }
  __syncthreads();

  // Phase C: serial exact top-8
  if (tid == 0) {
#pragma unroll 1
    for (int r = 0; r < 8; r++) {
      double bv = DNEG_INF;
      int bi = 0x7fffffff, bg = -1;
#pragma unroll
      for (int t = 0; t < NCAND; t++) {
        if (sc[t] > bv || (sc[t] == bv && cidx[t] < bi)) { bv = sc[t]; bi = cidx[t]; bg = t; }
      }
      s8[r] = bv; f8[r] = bi;
      sc[bg] = DNEG_INF;
    }
  }
  __syncthreads();
  if (tid < 8) {
    scores_out[q * 8 + tid] = (float)s8[tid];
    atomicAdd(&usage_out[f8[tid]], 1.0f);
  }

  // Phase D: gather 8 x 256 values
  {
    const int row = tid >> 5;
    const int c0 = (tid & 31) * 8;
    int idx = f8[row];
    float4 v0 = *(const float4*)(&values[(long long)idx * D + c0]);
    float4 v1 = *(const float4*)(&values[(long long)idx * D + c0 + 4]);
    long long obase = ((long long)q * 8 + row) * D + c0;
    *(float4*)(&out_rv[obase]) = v0;
    *(float4*)(&out_rv[obase + 4]) = v1;
  }
}

extern "C" void kernel_launch(void* const* d_in, const int* in_sizes, int n_in,
                              void* d_out, int out_size, void* d_ws, size_t ws_size,
                              hipStream_t stream) {
  (void)in_sizes; (void)n_in; (void)out_size; (void)ws_size;
  const float* query  = (const float*)d_in[0];
  const float* W      = (const float*)d_in[1];
  const float* b      = (const float*)d_in[2];
  const float* keys   = (const float*)d_in[3];
  const float* values = (const float*)d_in[4];
  const float* usage  = (const float*)d_in[5];

  float* out    = (float*)d_out;
  float* out_rv = out;                    // 2048*8*256
  float* out_sc = out + BQ * 8 * D;       // 2048*8
  float* out_us = out_sc + BQ * 8;        // 50000

  double*         q64n   = (double*)d_ws;                     // 524288 d  (4MB)
  double*         kinv64 = q64n + BQ * D;                     // 50000 d
  unsigned short* qbf    = (unsigned short*)(kinv64 + NKEYS); // 524288 us (1MB)
  unsigned short* kbf    = qbf + BQ * D;                      // 50176*256 (25.7MB)
  unsigned int*   cand_p = (unsigned int*)(kbf + (long long)NKPAD * D); // 2048*784 (6.4MB)

  hipLaunchKernelGGL(qnorm_kernel, dim3(BQ / 16), dim3(256), 0, stream, query, W, b, qbf, q64n);
  hipLaunchKernelGGL(kprep_kernel, dim3(NKPAD / 4), dim3(256), 0, stream, keys, usage, kinv64, kbf, out_us);
  // grid 6400 = 8 XCD-slots x 32 q-tiles x 25 chunk-groups (chunk >= 196 early-exits)
  hipLaunchKernelGGL(sim_mfma_kernel, dim3(6400), dim3(256), 0, stream, qbf, kbf, cand_p);
  hipLaunchKernelGGL(finalize_kernel, dim3(BQ), dim3(256), 0, stream, cand_p, q64n, keys, kinv64, values, out_sc, out_rv, out_us);
}